// Round 1
// baseline (1140.961 us; speedup 1.0000x reference)
//
#include <hip/hip_runtime.h>

// Problem constants
#define NTOK 32768
#define DDIM 1024
#define HDIM 512
#define CDIM 512
#define NEXP 8

typedef __attribute__((ext_vector_type(8))) __bf16 bf16x8;
typedef __attribute__((ext_vector_type(4))) float f32x4;
typedef __attribute__((ext_vector_type(4))) unsigned short us4;
typedef __attribute__((ext_vector_type(8))) unsigned short us8;

static __device__ __forceinline__ unsigned short f2bf(float f) {
  union { float f; unsigned u; } v; v.f = f;
  unsigned u = v.u;
  u += 0x7FFFu + ((u >> 16) & 1u);   // RNE round to bf16
  return (unsigned short)(u >> 16);
}

// ---------------------------------------------------------------------------
// Transpose [E][R][Cc] fp32 -> [E][Cc][R] bf16
// ---------------------------------------------------------------------------
__global__ __launch_bounds__(256) void transpose_bf16_kernel(
    const float* __restrict__ in, unsigned short* __restrict__ out,
    int R, int Cc) {
  __shared__ float tile[32][33];
  int e = blockIdx.z;
  int c0 = blockIdx.x * 32, r0 = blockIdx.y * 32;
  const float* src = in + (size_t)e * R * Cc;
  unsigned short* dst = out + (size_t)e * R * Cc;
  int tx = threadIdx.x, ty = threadIdx.y;  // (32, 8)
#pragma unroll
  for (int i = 0; i < 32; i += 8)
    tile[ty + i][tx] = src[(size_t)(r0 + ty + i) * Cc + (c0 + tx)];
  __syncthreads();
#pragma unroll
  for (int i = 0; i < 32; i += 8)
    dst[(size_t)(c0 + ty + i) * R + (r0 + tx)] = f2bf(tile[tx][ty + i]);
}

// ---------------------------------------------------------------------------
// Gating: logits (double accum) -> top2 -> softmax weights -> expert lists
// block = 256 (4 waves, 1 row per wave)
// ---------------------------------------------------------------------------
__global__ __launch_bounds__(256) void gate_kernel(
    const float* __restrict__ x, const float* __restrict__ Wg,
    const float* __restrict__ bg, int* __restrict__ counts,
    int* __restrict__ lists, float* __restrict__ wpair) {
  __shared__ float wgT[NEXP][DDIM];
  for (int i = threadIdx.x; i < DDIM * NEXP; i += 256) {
    int d = i >> 3, e = i & 7;
    wgT[e][d] = Wg[(size_t)d * NEXP + e];
  }
  __syncthreads();
  int wave = threadIdx.x >> 6, lane = threadIdx.x & 63;
  int n = blockIdx.x * 4 + wave;
  const float* xr = x + (size_t)n * DDIM;
  double acc[NEXP];
#pragma unroll
  for (int e = 0; e < NEXP; ++e) acc[e] = 0.0;
  for (int it = 0; it < DDIM / 64; ++it) {
    int d = it * 64 + lane;
    float xv = xr[d];
#pragma unroll
    for (int e = 0; e < NEXP; ++e) acc[e] += (double)xv * (double)wgT[e][d];
  }
#pragma unroll
  for (int e = 0; e < NEXP; ++e) {
    double v = acc[e];
#pragma unroll
    for (int off = 32; off > 0; off >>= 1) v += __shfl_xor(v, off, 64);
    acc[e] = v;
  }
  if (lane == 0) {
    float lg[NEXP];
#pragma unroll
    for (int e = 0; e < NEXP; ++e) lg[e] = (float)acc[e] + bg[e];
    int e0 = 0;
#pragma unroll
    for (int e = 1; e < NEXP; ++e) if (lg[e] > lg[e0]) e0 = e;   // earliest on tie
    int e1 = (e0 == 0) ? 1 : 0;
#pragma unroll
    for (int e = 0; e < NEXP; ++e)
      if (e != e0 && lg[e] > lg[e1]) e1 = e;                     // earliest on tie
    float v0 = lg[e0], v1 = lg[e1];
    float w1 = 1.0f / (1.0f + expf(v0 - v1));
    float w0 = 1.0f - w1;
    int r0 = atomicAdd(&counts[e0], 1);
    int r1 = atomicAdd(&counts[e1], 1);
    lists[e0 * NTOK + r0] = n * 2;
    lists[e1 * NTOK + r1] = n * 2 + 1;
    wpair[n * 2] = w0;
    wpair[n * 2 + 1] = w1;
  }
}

// ---------------------------------------------------------------------------
// GEMM tiles: BM=BN=128, BK=64, 4 waves (2x2 of 64x64), LDS pitch 72
// ---------------------------------------------------------------------------
#define BM 128
#define BN 128
#define BK 64
#define PITCH 72

// GEMM1: h[p, :] = relu( x[tok(p), :] @ W1t[e]^T + b1[e] )   (bf16 out)
__global__ __launch_bounds__(256) void gemm1_kernel(
    const float* __restrict__ x, const unsigned short* __restrict__ W1t,
    const float* __restrict__ b1, const int* __restrict__ lists,
    const int* __restrict__ counts, unsigned short* __restrict__ h) {
  int e = blockIdx.z;
  int ne = counts[e];
  int row0 = blockIdx.y * BM;
  if (row0 >= ne) return;
  int col0 = blockIdx.x * BN;

  __shared__ unsigned short sA[BM * PITCH];
  __shared__ unsigned short sB[BN * PITCH];
  __shared__ int sTok[BM];

  int t = threadIdx.x;
  if (t < BM) {
    int r = row0 + t;
    sTok[t] = (r < ne) ? lists[e * NTOK + r] : -1;
  }
  __syncthreads();

  // A staging: 8 passes of 16 rows; lane pattern r=t>>4 (0..15), kq=t&15 (float4)
  int arow = t >> 4, akq = t & 15;
  const float* aSrc[8];
  int aWoff[8];
#pragma unroll
  for (int j = 0; j < 8; ++j) {
    int p = sTok[j * 16 + arow];
    int tok = (p < 0) ? 0 : (p >> 1);
    aSrc[j] = x + (size_t)tok * DDIM + akq * 4;
    aWoff[j] = (j * 16 + arow) * PITCH + akq * 4;
  }
  // B staging: 4 passes of 32 cols; c=t>>3 (0..31), kq=t&7 (8 bf16)
  int brow = t >> 3, bkq = t & 7;
  const unsigned short* bSrc[4];
  int bWoff[4];
#pragma unroll
  for (int j = 0; j < 4; ++j) {
    int c = col0 + j * 32 + brow;
    bSrc[j] = W1t + ((size_t)e * HDIM + c) * DDIM + bkq * 8;
    bWoff[j] = (j * 32 + brow) * PITCH + bkq * 8;
  }

  int wave = t >> 6, lane = t & 63;
  int wr = wave >> 1, wc = wave & 1;
  int aBase = (wr * 64 + (lane & 15)) * PITCH + (lane >> 4) * 8;
  int bBase = (wc * 64 + (lane & 15)) * PITCH + (lane >> 4) * 8;

  f32x4 acc[4][4];
#pragma unroll
  for (int m = 0; m < 4; ++m)
#pragma unroll
    for (int nn = 0; nn < 4; ++nn) acc[m][nn] = (f32x4)0.0f;

  f32x4 aReg[8];
  us8 bReg[4];
  // prologue: load tile 0, store to LDS
#pragma unroll
  for (int j = 0; j < 8; ++j) aReg[j] = *(const f32x4*)(aSrc[j]);
#pragma unroll
  for (int j = 0; j < 4; ++j) bReg[j] = *(const us8*)(bSrc[j]);
#pragma unroll
  for (int j = 0; j < 8; ++j) {
    us4 v;
#pragma unroll
    for (int q = 0; q < 4; ++q) v[q] = f2bf(aReg[j][q]);
    *(us4*)&sA[aWoff[j]] = v;
  }
#pragma unroll
  for (int j = 0; j < 4; ++j) *(us8*)&sB[bWoff[j]] = bReg[j];
  __syncthreads();

  const int NKT = DDIM / BK;  // 16
  for (int kt = 0; kt < NKT; ++kt) {
    if (kt + 1 < NKT) {
#pragma unroll
      for (int j = 0; j < 8; ++j) aReg[j] = *(const f32x4*)(aSrc[j] + (kt + 1) * BK);
#pragma unroll
      for (int j = 0; j < 4; ++j) bReg[j] = *(const us8*)(bSrc[j] + (kt + 1) * BK);
    }
#pragma unroll
    for (int ks = 0; ks < 2; ++ks) {
      bf16x8 af[4], bfr[4];
#pragma unroll
      for (int m = 0; m < 4; ++m)
        af[m] = *(const bf16x8*)&sA[aBase + m * 16 * PITCH + ks * 32];
#pragma unroll
      for (int nn = 0; nn < 4; ++nn)
        bfr[nn] = *(const bf16x8*)&sB[bBase + nn * 16 * PITCH + ks * 32];
#pragma unroll
      for (int m = 0; m < 4; ++m)
#pragma unroll
        for (int nn = 0; nn < 4; ++nn)
          acc[m][nn] = __builtin_amdgcn_mfma_f32_16x16x32_bf16(
              af[m], bfr[nn], acc[m][nn], 0, 0, 0);
    }
    __syncthreads();
    if (kt + 1 < NKT) {
#pragma unroll
      for (int j = 0; j < 8; ++j) {
        us4 v;
#pragma unroll
        for (int q = 0; q < 4; ++q) v[q] = f2bf(aReg[j][q]);
        *(us4*)&sA[aWoff[j]] = v;
      }
#pragma unroll
      for (int j = 0; j < 4; ++j) *(us8*)&sB[bWoff[j]] = bReg[j];
    }
    __syncthreads();
  }

  // epilogue: relu(acc + b1) -> bf16 h rows
  int cBase = col0 + wc * 64 + (lane & 15);
  float b1c[4];
#pragma unroll
  for (int nn = 0; nn < 4; ++nn) b1c[nn] = b1[e * HDIM + cBase + nn * 16];
#pragma unroll
  for (int m = 0; m < 4; ++m) {
#pragma unroll
    for (int q = 0; q < 4; ++q) {
      int rloc = wr * 64 + m * 16 + (lane >> 4) * 4 + q;
      if (row0 + rloc < ne) {
        int p = sTok[rloc];
        unsigned short* hr = h + (size_t)p * HDIM;
#pragma unroll
        for (int nn = 0; nn < 4; ++nn) {
          float v = acc[m][nn][q] + b1c[nn];
          v = fmaxf(v, 0.0f);
          hr[cBase + nn * 16] = f2bf(v);
        }
      }
    }
  }
}

// GEMM2: out[tok(p), :] += w(p) * ( h[p, :] @ W2t[e]^T + b2[e] )
__global__ __launch_bounds__(256) void gemm2_kernel(
    const unsigned short* __restrict__ h, const unsigned short* __restrict__ W2t,
    const float* __restrict__ b2, const int* __restrict__ lists,
    const int* __restrict__ counts, const float* __restrict__ wpair,
    float* __restrict__ out) {
  int e = blockIdx.z;
  int ne = counts[e];
  int row0 = blockIdx.y * BM;
  if (row0 >= ne) return;
  int col0 = blockIdx.x * BN;

  __shared__ unsigned short sA[BM * PITCH];
  __shared__ unsigned short sB[BN * PITCH];
  __shared__ int sTok[BM];
  __shared__ float sW[BM];

  int t = threadIdx.x;
  if (t < BM) {
    int r = row0 + t;
    int p = (r < ne) ? lists[e * NTOK + r] : -1;
    sTok[t] = p;
    sW[t] = (p >= 0) ? wpair[p] : 0.0f;
  }
  __syncthreads();

  int arow = t >> 3, akq = t & 7;  // 32 rows per pass, 8 bf16 per lane
  const unsigned short* aSrc[4];
  const unsigned short* bSrc[4];
  int wOff[4];
#pragma unroll
  for (int j = 0; j < 4; ++j) {
    int p = sTok[j * 32 + arow];
    int pp = (p < 0) ? 0 : p;
    aSrc[j] = h + (size_t)pp * HDIM + akq * 8;
    int c = col0 + j * 32 + arow;
    bSrc[j] = W2t + ((size_t)e * CDIM + c) * HDIM + akq * 8;
    wOff[j] = (j * 32 + arow) * PITCH + akq * 8;
  }

  int wave = t >> 6, lane = t & 63;
  int wr = wave >> 1, wc = wave & 1;
  int aBase = (wr * 64 + (lane & 15)) * PITCH + (lane >> 4) * 8;
  int bBase = (wc * 64 + (lane & 15)) * PITCH + (lane >> 4) * 8;

  f32x4 acc[4][4];
#pragma unroll
  for (int m = 0; m < 4; ++m)
#pragma unroll
    for (int nn = 0; nn < 4; ++nn) acc[m][nn] = (f32x4)0.0f;

  us8 aReg[4], bReg[4];
#pragma unroll
  for (int j = 0; j < 4; ++j) aReg[j] = *(const us8*)(aSrc[j]);
#pragma unroll
  for (int j = 0; j < 4; ++j) bReg[j] = *(const us8*)(bSrc[j]);
#pragma unroll
  for (int j = 0; j < 4; ++j) *(us8*)&sA[wOff[j]] = aReg[j];
#pragma unroll
  for (int j = 0; j < 4; ++j) *(us8*)&sB[wOff[j]] = bReg[j];
  __syncthreads();

  const int NKT = HDIM / BK;  // 8
  for (int kt = 0; kt < NKT; ++kt) {
    if (kt + 1 < NKT) {
#pragma unroll
      for (int j = 0; j < 4; ++j) aReg[j] = *(const us8*)(aSrc[j] + (kt + 1) * BK);
#pragma unroll
      for (int j = 0; j < 4; ++j) bReg[j] = *(const us8*)(bSrc[j] + (kt + 1) * BK);
    }
#pragma unroll
    for (int ks = 0; ks < 2; ++ks) {
      bf16x8 af[4], bfr[4];
#pragma unroll
      for (int m = 0; m < 4; ++m)
        af[m] = *(const bf16x8*)&sA[aBase + m * 16 * PITCH + ks * 32];
#pragma unroll
      for (int nn = 0; nn < 4; ++nn)
        bfr[nn] = *(const bf16x8*)&sB[bBase + nn * 16 * PITCH + ks * 32];
#pragma unroll
      for (int m = 0; m < 4; ++m)
#pragma unroll
        for (int nn = 0; nn < 4; ++nn)
          acc[m][nn] = __builtin_amdgcn_mfma_f32_16x16x32_bf16(
              af[m], bfr[nn], acc[m][nn], 0, 0, 0);
    }
    __syncthreads();
    if (kt + 1 < NKT) {
#pragma unroll
      for (int j = 0; j < 4; ++j) *(us8*)&sA[wOff[j]] = aReg[j];
#pragma unroll
      for (int j = 0; j < 4; ++j) *(us8*)&sB[wOff[j]] = bReg[j];
    }
    __syncthreads();
  }

  int cBase = col0 + wc * 64 + (lane & 15);
  float b2c[4];
#pragma unroll
  for (int nn = 0; nn < 4; ++nn) b2c[nn] = b2[e * CDIM + cBase + nn * 16];
#pragma unroll
  for (int m = 0; m < 4; ++m) {
#pragma unroll
    for (int q = 0; q < 4; ++q) {
      int rloc = wr * 64 + m * 16 + (lane >> 4) * 4 + q;
      if (row0 + rloc < ne) {
        int p = sTok[rloc];
        float wgt = sW[rloc];
        int tok = p >> 1;
        float* orow = out + (size_t)tok * CDIM;
#pragma unroll
        for (int nn = 0; nn < 4; ++nn) {
          float v = (acc[m][nn][q] + b2c[nn]) * wgt;
          atomicAdd(&orow[cBase + nn * 16], v);
        }
      }
    }
  }
}

// ---------------------------------------------------------------------------
extern "C" void kernel_launch(void* const* d_in, const int* in_sizes, int n_in,
                              void* d_out, int out_size, void* d_ws, size_t ws_size,
                              hipStream_t stream) {
  const float* x  = (const float*)d_in[0];
  const float* W1 = (const float*)d_in[1];
  const float* b1 = (const float*)d_in[2];
  const float* W2 = (const float*)d_in[3];
  const float* b2 = (const float*)d_in[4];
  const float* Wg = (const float*)d_in[5];
  const float* bg = (const float*)d_in[6];
  float* out = (float*)d_out;
  char* ws = (char*)d_ws;

  // workspace layout (≈77.3 MiB total)
  int* counts = (int*)ws;                                   // 32 B
  float* wpair = (float*)(ws + 256);                        // 256 KiB
  int* lists = (int*)(ws + 256 + 262144);                   // 1 MiB
  unsigned short* W1t = (unsigned short*)(ws + 256 + 262144 + 1048576);  // 8 MiB
  unsigned short* W2t = W1t + (size_t)NEXP * HDIM * DDIM;   // 4 MiB
  unsigned short* hbuf = W2t + (size_t)NEXP * CDIM * HDIM;  // 64 MiB

  hipMemsetAsync(counts, 0, NEXP * sizeof(int), stream);
  hipMemsetAsync(d_out, 0, (size_t)out_size * sizeof(float), stream);

  hipLaunchKernelGGL(transpose_bf16_kernel, dim3(HDIM / 32, DDIM / 32, NEXP),
                     dim3(32, 8), 0, stream, W1, W1t, DDIM, HDIM);
  hipLaunchKernelGGL(transpose_bf16_kernel, dim3(CDIM / 32, HDIM / 32, NEXP),
                     dim3(32, 8), 0, stream, W2, W2t, HDIM, CDIM);
  hipLaunchKernelGGL(gate_kernel, dim3(NTOK / 4), dim3(256), 0, stream,
                     x, Wg, bg, counts, lists, wpair);
  hipLaunchKernelGGL(gemm1_kernel, dim3(HDIM / BN, NTOK / BM, NEXP), dim3(256),
                     0, stream, x, W1t, b1, lists, counts, hbuf);
  hipLaunchKernelGGL(gemm2_kernel, dim3(CDIM / BN, NTOK / BM, NEXP), dim3(256),
                     0, stream, hbuf, W2t, b2, lists, counts, wpair, out);
}

// Round 2
// 540.234 us; speedup vs baseline: 2.1120x; 2.1120x over previous
//
#include <hip/hip_runtime.h>

// Problem constants
#define NTOK 32768
#define DDIM 1024
#define HDIM 512
#define CDIM 512
#define NEXP 8

typedef __attribute__((ext_vector_type(8))) __bf16 bf16x8;
typedef __attribute__((ext_vector_type(4))) float f32x4;
typedef __attribute__((ext_vector_type(4))) unsigned short us4;
typedef __attribute__((ext_vector_type(8))) unsigned short us8;

static __device__ __forceinline__ unsigned short f2bf(float f) {
  union { float f; unsigned u; } v; v.f = f;
  unsigned u = v.u;
  u += 0x7FFFu + ((u >> 16) & 1u);   // RNE round to bf16
  return (unsigned short)(u >> 16);
}

// ---------------------------------------------------------------------------
// Transpose [E][R][Cc] fp32 -> [E][Cc][R] bf16
// ---------------------------------------------------------------------------
__global__ __launch_bounds__(256) void transpose_bf16_kernel(
    const float* __restrict__ in, unsigned short* __restrict__ out,
    int R, int Cc) {
  __shared__ float tile[32][33];
  int e = blockIdx.z;
  int c0 = blockIdx.x * 32, r0 = blockIdx.y * 32;
  const float* src = in + (size_t)e * R * Cc;
  unsigned short* dst = out + (size_t)e * R * Cc;
  int tx = threadIdx.x, ty = threadIdx.y;  // (32, 8)
#pragma unroll
  for (int i = 0; i < 32; i += 8)
    tile[ty + i][tx] = src[(size_t)(r0 + ty + i) * Cc + (c0 + tx)];
  __syncthreads();
#pragma unroll
  for (int i = 0; i < 32; i += 8)
    dst[(size_t)(c0 + ty + i) * R + (r0 + tx)] = f2bf(tile[tx][ty + i]);
}

// ---------------------------------------------------------------------------
// Gate logits: double-accum logits -> per-row top2 + softmax weights.
// NO atomics. block=256 (4 waves); each wave does 4 rows -> 16 rows/block.
// ---------------------------------------------------------------------------
__global__ __launch_bounds__(256) void gate_logits_kernel(
    const float* __restrict__ x, const float* __restrict__ Wg,
    const float* __restrict__ bg, int* __restrict__ sel,
    float* __restrict__ wpair) {
  __shared__ float wgT[NEXP][DDIM];
  // conflict-free staging: consecutive threads write consecutive d (same e)
  for (int i = threadIdx.x; i < DDIM * NEXP; i += 256) {
    int d = i & (DDIM - 1), e = i >> 10;
    wgT[e][d] = Wg[(size_t)d * NEXP + e];
  }
  __syncthreads();
  int wave = threadIdx.x >> 6, lane = threadIdx.x & 63;
#pragma unroll 1
  for (int r = 0; r < 4; ++r) {
    int n = blockIdx.x * 16 + wave * 4 + r;
    const float* xr = x + (size_t)n * DDIM;
    double acc[NEXP];
#pragma unroll
    for (int e = 0; e < NEXP; ++e) acc[e] = 0.0;
    for (int it = 0; it < DDIM / 64; ++it) {
      int d = it * 64 + lane;
      float xv = xr[d];
#pragma unroll
      for (int e = 0; e < NEXP; ++e) acc[e] += (double)xv * (double)wgT[e][d];
    }
#pragma unroll
    for (int e = 0; e < NEXP; ++e) {
      double v = acc[e];
#pragma unroll
      for (int off = 32; off > 0; off >>= 1) v += __shfl_xor(v, off, 64);
      acc[e] = v;
    }
    if (lane == 0) {
      float lg[NEXP];
#pragma unroll
      for (int e = 0; e < NEXP; ++e) lg[e] = (float)acc[e] + bg[e];
      int e0 = 0;
#pragma unroll
      for (int e = 1; e < NEXP; ++e) if (lg[e] > lg[e0]) e0 = e;   // earliest on tie
      int e1 = (e0 == 0) ? 1 : 0;
#pragma unroll
      for (int e = 0; e < NEXP; ++e)
        if (e != e0 && lg[e] > lg[e1]) e1 = e;                     // earliest on tie
      float v0 = lg[e0], v1 = lg[e1];
      float w1 = 1.0f / (1.0f + expf(v0 - v1));
      float w0 = 1.0f - w1;
      sel[n] = e0 | (e1 << 4);
      wpair[n * 2] = w0;
      wpair[n * 2 + 1] = w1;
    }
  }
}

// ---------------------------------------------------------------------------
// Build per-expert pair lists via deterministic block-wide prefix scan.
// grid = NEXP blocks, 1024 threads; thread t owns rows [t*32, t*32+32).
// ---------------------------------------------------------------------------
__global__ __launch_bounds__(1024) void build_lists_kernel(
    const int* __restrict__ sel, int* __restrict__ counts,
    int* __restrict__ lists) {
  int e = blockIdx.x;
  int t = threadIdx.x;
  __shared__ int sc[1024];
  int base = t * (NTOK / 1024);
  int cnt = 0;
#pragma unroll
  for (int i = 0; i < NTOK / 1024; ++i) {
    int s = sel[base + i];
    cnt += ((s & 15) == e) || (((s >> 4) & 15) == e);
  }
  sc[t] = cnt;
  __syncthreads();
  // Hillis-Steele inclusive scan over 1024 entries
  for (int d = 1; d < 1024; d <<= 1) {
    int v = (t >= d) ? sc[t - d] : 0;
    __syncthreads();
    sc[t] += v;
    __syncthreads();
  }
  int off = sc[t] - cnt;
#pragma unroll
  for (int i = 0; i < NTOK / 1024; ++i) {
    int s = sel[base + i];
    if ((s & 15) == e)
      lists[e * NTOK + off++] = (base + i) * 2;
    else if (((s >> 4) & 15) == e)
      lists[e * NTOK + off++] = (base + i) * 2 + 1;
  }
  if (t == 1023) counts[e] = sc[1023];
}

// ---------------------------------------------------------------------------
// GEMM tiles: BM=BN=128, BK=64, 4 waves (2x2 of 64x64), LDS pitch 72
// ---------------------------------------------------------------------------
#define BM 128
#define BN 128
#define BK 64
#define PITCH 72

// GEMM1: h[p, :] = relu( x[tok(p), :] @ W1t[e]^T + b1[e] )   (bf16 out)
__global__ __launch_bounds__(256) void gemm1_kernel(
    const float* __restrict__ x, const unsigned short* __restrict__ W1t,
    const float* __restrict__ b1, const int* __restrict__ lists,
    const int* __restrict__ counts, unsigned short* __restrict__ h) {
  int e = blockIdx.z;
  int ne = counts[e];
  int row0 = blockIdx.y * BM;
  if (row0 >= ne) return;
  int col0 = blockIdx.x * BN;

  __shared__ unsigned short sA[BM * PITCH];
  __shared__ unsigned short sB[BN * PITCH];
  __shared__ int sTok[BM];

  int t = threadIdx.x;
  if (t < BM) {
    int r = row0 + t;
    sTok[t] = (r < ne) ? lists[e * NTOK + r] : -1;
  }
  __syncthreads();

  // A staging: 8 passes of 16 rows; r=t>>4 (0..15), kq=t&15 (float4)
  int arow = t >> 4, akq = t & 15;
  const float* aSrc[8];
  int aWoff[8];
#pragma unroll
  for (int j = 0; j < 8; ++j) {
    int p = sTok[j * 16 + arow];
    int tok = (p < 0) ? 0 : (p >> 1);
    aSrc[j] = x + (size_t)tok * DDIM + akq * 4;
    aWoff[j] = (j * 16 + arow) * PITCH + akq * 4;
  }
  // B staging: 4 passes of 32 cols; c=t>>3 (0..31), kq=t&7 (8 bf16)
  int brow = t >> 3, bkq = t & 7;
  const unsigned short* bSrc[4];
  int bWoff[4];
#pragma unroll
  for (int j = 0; j < 4; ++j) {
    int c = col0 + j * 32 + brow;
    bSrc[j] = W1t + ((size_t)e * HDIM + c) * DDIM + bkq * 8;
    bWoff[j] = (j * 32 + brow) * PITCH + bkq * 8;
  }

  int wave = t >> 6, lane = t & 63;
  int wr = wave >> 1, wc = wave & 1;
  int aBase = (wr * 64 + (lane & 15)) * PITCH + (lane >> 4) * 8;
  int bBase = (wc * 64 + (lane & 15)) * PITCH + (lane >> 4) * 8;

  f32x4 acc[4][4];
#pragma unroll
  for (int m = 0; m < 4; ++m)
#pragma unroll
    for (int nn = 0; nn < 4; ++nn) acc[m][nn] = (f32x4)0.0f;

  f32x4 aReg[8];
  us8 bReg[4];
#pragma unroll
  for (int j = 0; j < 8; ++j) aReg[j] = *(const f32x4*)(aSrc[j]);
#pragma unroll
  for (int j = 0; j < 4; ++j) bReg[j] = *(const us8*)(bSrc[j]);
#pragma unroll
  for (int j = 0; j < 8; ++j) {
    us4 v;
#pragma unroll
    for (int q = 0; q < 4; ++q) v[q] = f2bf(aReg[j][q]);
    *(us4*)&sA[aWoff[j]] = v;
  }
#pragma unroll
  for (int j = 0; j < 4; ++j) *(us8*)&sB[bWoff[j]] = bReg[j];
  __syncthreads();

  const int NKT = DDIM / BK;  // 16
  for (int kt = 0; kt < NKT; ++kt) {
    if (kt + 1 < NKT) {
#pragma unroll
      for (int j = 0; j < 8; ++j) aReg[j] = *(const f32x4*)(aSrc[j] + (kt + 1) * BK);
#pragma unroll
      for (int j = 0; j < 4; ++j) bReg[j] = *(const us8*)(bSrc[j] + (kt + 1) * BK);
    }
#pragma unroll
    for (int ks = 0; ks < 2; ++ks) {
      bf16x8 af[4], bfr[4];
#pragma unroll
      for (int m = 0; m < 4; ++m)
        af[m] = *(const bf16x8*)&sA[aBase + m * 16 * PITCH + ks * 32];
#pragma unroll
      for (int nn = 0; nn < 4; ++nn)
        bfr[nn] = *(const bf16x8*)&sB[bBase + nn * 16 * PITCH + ks * 32];
#pragma unroll
      for (int m = 0; m < 4; ++m)
#pragma unroll
        for (int nn = 0; nn < 4; ++nn)
          acc[m][nn] = __builtin_amdgcn_mfma_f32_16x16x32_bf16(
              af[m], bfr[nn], acc[m][nn], 0, 0, 0);
    }
    __syncthreads();
    if (kt + 1 < NKT) {
#pragma unroll
      for (int j = 0; j < 8; ++j) {
        us4 v;
#pragma unroll
        for (int q = 0; q < 4; ++q) v[q] = f2bf(aReg[j][q]);
        *(us4*)&sA[aWoff[j]] = v;
      }
#pragma unroll
      for (int j = 0; j < 4; ++j) *(us8*)&sB[bWoff[j]] = bReg[j];
    }
    __syncthreads();
  }

  int cBase = col0 + wc * 64 + (lane & 15);
  float b1c[4];
#pragma unroll
  for (int nn = 0; nn < 4; ++nn) b1c[nn] = b1[e * HDIM + cBase + nn * 16];
#pragma unroll
  for (int m = 0; m < 4; ++m) {
#pragma unroll
    for (int q = 0; q < 4; ++q) {
      int rloc = wr * 64 + m * 16 + (lane >> 4) * 4 + q;
      if (row0 + rloc < ne) {
        int p = sTok[rloc];
        unsigned short* hr = h + (size_t)p * HDIM;
#pragma unroll
        for (int nn = 0; nn < 4; ++nn) {
          float v = acc[m][nn][q] + b1c[nn];
          v = fmaxf(v, 0.0f);
          hr[cBase + nn * 16] = f2bf(v);
        }
      }
    }
  }
}

// GEMM2: out[tok(p), :] += w(p) * ( h[p, :] @ W2t[e]^T + b2[e] )
__global__ __launch_bounds__(256) void gemm2_kernel(
    const unsigned short* __restrict__ h, const unsigned short* __restrict__ W2t,
    const float* __restrict__ b2, const int* __restrict__ lists,
    const int* __restrict__ counts, const float* __restrict__ wpair,
    float* __restrict__ out) {
  int e = blockIdx.z;
  int ne = counts[e];
  int row0 = blockIdx.y * BM;
  if (row0 >= ne) return;
  int col0 = blockIdx.x * BN;

  __shared__ unsigned short sA[BM * PITCH];
  __shared__ unsigned short sB[BN * PITCH];
  __shared__ int sTok[BM];
  __shared__ float sW[BM];

  int t = threadIdx.x;
  if (t < BM) {
    int r = row0 + t;
    int p = (r < ne) ? lists[e * NTOK + r] : -1;
    sTok[t] = p;
    sW[t] = (p >= 0) ? wpair[p] : 0.0f;
  }
  __syncthreads();

  int arow = t >> 3, akq = t & 7;
  const unsigned short* aSrc[4];
  const unsigned short* bSrc[4];
  int wOff[4];
#pragma unroll
  for (int j = 0; j < 4; ++j) {
    int p = sTok[j * 32 + arow];
    int pp = (p < 0) ? 0 : p;
    aSrc[j] = h + (size_t)pp * HDIM + akq * 8;
    int c = col0 + j * 32 + arow;
    bSrc[j] = W2t + ((size_t)e * CDIM + c) * HDIM + akq * 8;
    wOff[j] = (j * 32 + arow) * PITCH + akq * 8;
  }

  int wave = t >> 6, lane = t & 63;
  int wr = wave >> 1, wc = wave & 1;
  int aBase = (wr * 64 + (lane & 15)) * PITCH + (lane >> 4) * 8;
  int bBase = (wc * 64 + (lane & 15)) * PITCH + (lane >> 4) * 8;

  f32x4 acc[4][4];
#pragma unroll
  for (int m = 0; m < 4; ++m)
#pragma unroll
    for (int nn = 0; nn < 4; ++nn) acc[m][nn] = (f32x4)0.0f;

  us8 aReg[4], bReg[4];
#pragma unroll
  for (int j = 0; j < 4; ++j) aReg[j] = *(const us8*)(aSrc[j]);
#pragma unroll
  for (int j = 0; j < 4; ++j) bReg[j] = *(const us8*)(bSrc[j]);
#pragma unroll
  for (int j = 0; j < 4; ++j) *(us8*)&sA[wOff[j]] = aReg[j];
#pragma unroll
  for (int j = 0; j < 4; ++j) *(us8*)&sB[wOff[j]] = bReg[j];
  __syncthreads();

  const int NKT = HDIM / BK;  // 8
  for (int kt = 0; kt < NKT; ++kt) {
    if (kt + 1 < NKT) {
#pragma unroll
      for (int j = 0; j < 4; ++j) aReg[j] = *(const us8*)(aSrc[j] + (kt + 1) * BK);
#pragma unroll
      for (int j = 0; j < 4; ++j) bReg[j] = *(const us8*)(bSrc[j] + (kt + 1) * BK);
    }
#pragma unroll
    for (int ks = 0; ks < 2; ++ks) {
      bf16x8 af[4], bfr[4];
#pragma unroll
      for (int m = 0; m < 4; ++m)
        af[m] = *(const bf16x8*)&sA[aBase + m * 16 * PITCH + ks * 32];
#pragma unroll
      for (int nn = 0; nn < 4; ++nn)
        bfr[nn] = *(const bf16x8*)&sB[bBase + nn * 16 * PITCH + ks * 32];
#pragma unroll
      for (int m = 0; m < 4; ++m)
#pragma unroll
        for (int nn = 0; nn < 4; ++nn)
          acc[m][nn] = __builtin_amdgcn_mfma_f32_16x16x32_bf16(
              af[m], bfr[nn], acc[m][nn], 0, 0, 0);
    }
    __syncthreads();
    if (kt + 1 < NKT) {
#pragma unroll
      for (int j = 0; j < 4; ++j) *(us8*)&sA[wOff[j]] = aReg[j];
#pragma unroll
      for (int j = 0; j < 4; ++j) *(us8*)&sB[wOff[j]] = bReg[j];
    }
    __syncthreads();
  }

  int cBase = col0 + wc * 64 + (lane & 15);
  float b2c[4];
#pragma unroll
  for (int nn = 0; nn < 4; ++nn) b2c[nn] = b2[e * CDIM + cBase + nn * 16];
#pragma unroll
  for (int m = 0; m < 4; ++m) {
#pragma unroll
    for (int q = 0; q < 4; ++q) {
      int rloc = wr * 64 + m * 16 + (lane >> 4) * 4 + q;
      if (row0 + rloc < ne) {
        int p = sTok[rloc];
        float wgt = sW[rloc];
        int tok = p >> 1;
        float* orow = out + (size_t)tok * CDIM;
#pragma unroll
        for (int nn = 0; nn < 4; ++nn) {
          float v = (acc[m][nn][q] + b2c[nn]) * wgt;
          atomicAdd(&orow[cBase + nn * 16], v);
        }
      }
    }
  }
}

// ---------------------------------------------------------------------------
extern "C" void kernel_launch(void* const* d_in, const int* in_sizes, int n_in,
                              void* d_out, int out_size, void* d_ws, size_t ws_size,
                              hipStream_t stream) {
  const float* x  = (const float*)d_in[0];
  const float* W1 = (const float*)d_in[1];
  const float* b1 = (const float*)d_in[2];
  const float* W2 = (const float*)d_in[3];
  const float* b2 = (const float*)d_in[4];
  const float* Wg = (const float*)d_in[5];
  const float* bg = (const float*)d_in[6];
  float* out = (float*)d_out;
  char* ws = (char*)d_ws;

  // workspace layout
  int* counts = (int*)ws;                                    // 256 B
  float* wpair = (float*)(ws + 256);                         // 256 KiB
  int* sel = (int*)(ws + 256 + 262144);                      // 128 KiB
  int* lists = (int*)(ws + 256 + 262144 + 131072);           // 1 MiB
  unsigned short* W1t = (unsigned short*)(ws + 256 + 262144 + 131072 + 1048576);
  unsigned short* W2t = W1t + (size_t)NEXP * HDIM * DDIM;    // +8 MiB
  unsigned short* hbuf = W2t + (size_t)NEXP * CDIM * HDIM;   // +4 MiB, hbuf 64 MiB

  hipMemsetAsync(d_out, 0, (size_t)out_size * sizeof(float), stream);

  hipLaunchKernelGGL(transpose_bf16_kernel, dim3(HDIM / 32, DDIM / 32, NEXP),
                     dim3(32, 8), 0, stream, W1, W1t, DDIM, HDIM);
  hipLaunchKernelGGL(transpose_bf16_kernel, dim3(CDIM / 32, HDIM / 32, NEXP),
                     dim3(32, 8), 0, stream, W2, W2t, HDIM, CDIM);
  hipLaunchKernelGGL(gate_logits_kernel, dim3(NTOK / 16), dim3(256), 0, stream,
                     x, Wg, bg, sel, wpair);
  hipLaunchKernelGGL(build_lists_kernel, dim3(NEXP), dim3(1024), 0, stream,
                     sel, counts, lists);
  hipLaunchKernelGGL(gemm1_kernel, dim3(HDIM / BN, NTOK / BM, NEXP), dim3(256),
                     0, stream, x, W1t, b1, lists, counts, hbuf);
  hipLaunchKernelGGL(gemm2_kernel, dim3(CDIM / BN, NTOK / BM, NEXP), dim3(256),
                     0, stream, hbuf, W2t, b2, lists, counts, wpair, out);
}

// Round 3
// 453.898 us; speedup vs baseline: 2.5137x; 1.1902x over previous
//
#include <hip/hip_runtime.h>

// Problem constants
#define NTOK 32768
#define DDIM 1024
#define HDIM 512
#define CDIM 512
#define NEXP 8

#define BM 128
#define BN 128
#define BK 64
#define PITCH 72
#define MAXTILE 520   // sum ceil(ne/128) <= 512 + 8

typedef __attribute__((ext_vector_type(8))) __bf16 bf16x8;
typedef __attribute__((ext_vector_type(4))) float f32x4;
typedef __attribute__((ext_vector_type(4))) unsigned short us4;
typedef __attribute__((ext_vector_type(8))) unsigned short us8;

static __device__ __forceinline__ unsigned short f2bf(float f) {
  union { float f; unsigned u; } v; v.f = f;
  unsigned u = v.u;
  u += 0x7FFFu + ((u >> 16) & 1u);   // RNE round to bf16
  return (unsigned short)(u >> 16);
}

// ---------------------------------------------------------------------------
// Transpose [E][R][Cc] fp32 -> [E][Cc][R] bf16
// ---------------------------------------------------------------------------
__global__ __launch_bounds__(256) void transpose_bf16_kernel(
    const float* __restrict__ in, unsigned short* __restrict__ out,
    int R, int Cc) {
  __shared__ float tile[32][33];
  int e = blockIdx.z;
  int c0 = blockIdx.x * 32, r0 = blockIdx.y * 32;
  const float* src = in + (size_t)e * R * Cc;
  unsigned short* dst = out + (size_t)e * R * Cc;
  int tx = threadIdx.x, ty = threadIdx.y;  // (32, 8)
#pragma unroll
  for (int i = 0; i < 32; i += 8)
    tile[ty + i][tx] = src[(size_t)(r0 + ty + i) * Cc + (c0 + tx)];
  __syncthreads();
#pragma unroll
  for (int i = 0; i < 32; i += 8)
    dst[(size_t)(c0 + ty + i) * R + (r0 + tx)] = f2bf(tile[tx][ty + i]);
}

// ---------------------------------------------------------------------------
// Gate: double-accum logits -> top2 + softmax weights; also emits xb (bf16 x).
// block=256 (4 waves); wave does 4 rows -> 16 rows/block. No atomics.
// ---------------------------------------------------------------------------
__global__ __launch_bounds__(256) void gate_logits_kernel(
    const float* __restrict__ x, const float* __restrict__ Wg,
    const float* __restrict__ bg, int* __restrict__ sel,
    float* __restrict__ wpair, unsigned short* __restrict__ xb) {
  __shared__ float wgT[NEXP][DDIM];
  for (int i = threadIdx.x; i < DDIM * NEXP; i += 256) {
    int d = i & (DDIM - 1), e = i >> 10;
    wgT[e][d] = Wg[(size_t)d * NEXP + e];
  }
  __syncthreads();
  int wave = threadIdx.x >> 6, lane = threadIdx.x & 63;
#pragma unroll 1
  for (int r = 0; r < 4; ++r) {
    int n = blockIdx.x * 16 + wave * 4 + r;
    const f32x4* xr = (const f32x4*)(x + (size_t)n * DDIM);
    unsigned short* xbr = xb + (size_t)n * DDIM;
    double acc[NEXP];
#pragma unroll
    for (int e = 0; e < NEXP; ++e) acc[e] = 0.0;
#pragma unroll
    for (int it = 0; it < DDIM / 256; ++it) {   // 4 iters of float4
      int dq = it * 64 + lane;
      f32x4 xv = xr[dq];
      us4 o;
#pragma unroll
      for (int q = 0; q < 4; ++q) o[q] = f2bf(xv[q]);
      *(us4*)&xbr[dq * 4] = o;
#pragma unroll
      for (int e = 0; e < NEXP; ++e) {
        f32x4 wv = *(const f32x4*)&wgT[e][dq * 4];
#pragma unroll
        for (int q = 0; q < 4; ++q) acc[e] += (double)xv[q] * (double)wv[q];
      }
    }
#pragma unroll
    for (int e = 0; e < NEXP; ++e) {
      double v = acc[e];
#pragma unroll
      for (int off = 32; off > 0; off >>= 1) v += __shfl_xor(v, off, 64);
      acc[e] = v;
    }
    if (lane == 0) {
      float lg[NEXP];
#pragma unroll
      for (int e = 0; e < NEXP; ++e) lg[e] = (float)acc[e] + bg[e];
      int e0 = 0;
#pragma unroll
      for (int e = 1; e < NEXP; ++e) if (lg[e] > lg[e0]) e0 = e;   // earliest on tie
      int e1 = (e0 == 0) ? 1 : 0;
#pragma unroll
      for (int e = 0; e < NEXP; ++e)
        if (e != e0 && lg[e] > lg[e1]) e1 = e;                     // earliest on tie
      float v0 = lg[e0], v1 = lg[e1];
      float w1 = 1.0f / (1.0f + expf(v0 - v1));
      float w0 = 1.0f - w1;
      sel[n] = e0 | (e1 << 4);
      wpair[n * 2] = w0;
      wpair[n * 2 + 1] = w1;
    }
  }
}

// ---------------------------------------------------------------------------
// Build per-expert pair lists via deterministic block-wide prefix scan.
// grid = NEXP blocks, 1024 threads; thread t owns rows [t*32, t*32+32).
// ---------------------------------------------------------------------------
__global__ __launch_bounds__(1024) void build_lists_kernel(
    const int* __restrict__ sel, int* __restrict__ counts,
    int* __restrict__ lists) {
  int e = blockIdx.x;
  int t = threadIdx.x;
  __shared__ int sc[1024];
  int base = t * (NTOK / 1024);
  int cnt = 0;
#pragma unroll
  for (int i = 0; i < NTOK / 1024; ++i) {
    int s = sel[base + i];
    cnt += ((s & 15) == e) || (((s >> 4) & 15) == e);
  }
  sc[t] = cnt;
  __syncthreads();
  for (int d = 1; d < 1024; d <<= 1) {
    int v = (t >= d) ? sc[t - d] : 0;
    __syncthreads();
    sc[t] += v;
    __syncthreads();
  }
  int off = sc[t] - cnt;
#pragma unroll
  for (int i = 0; i < NTOK / 1024; ++i) {
    int s = sel[base + i];
    if ((s & 15) == e)
      lists[e * NTOK + off++] = (base + i) * 2;
    else if (((s >> 4) & 15) == e)
      lists[e * NTOK + off++] = (base + i) * 2 + 1;
  }
  if (t == 1023) counts[e] = sc[1023];
}

// ---------------------------------------------------------------------------
// Tile table: tiles[0]=ntiles; tiles[1+2t]=expert, tiles[2+2t]=row0.
// ---------------------------------------------------------------------------
__global__ __launch_bounds__(256) void make_tiles_kernel(
    const int* __restrict__ counts, int* __restrict__ tiles) {
  __shared__ int off[NEXP + 1];
  int t = threadIdx.x;
  if (t == 0) {
    int s = 0;
    for (int e = 0; e < NEXP; ++e) { off[e] = s; s += (counts[e] + BM - 1) / BM; }
    off[NEXP] = s;
    tiles[0] = s;
  }
  __syncthreads();
  for (int e = 0; e < NEXP; ++e) {
    int base = off[e], cnt = off[e + 1] - off[e];
    for (int k = t; k < cnt; k += 256) {
      tiles[1 + 2 * (base + k)] = e;
      tiles[2 + 2 * (base + k)] = k * BM;
    }
  }
}

// ---------------------------------------------------------------------------
// XCD-chunked decode: grid = 65*4*8 = 2080 flat blocks.
// col-blocks of one row-tile -> ids i, i+8, i+16, i+24 (same XCD).
// ---------------------------------------------------------------------------
static __device__ __forceinline__ bool decode_tile(
    const int* tiles, const int* counts, int& e, int& ne, int& row0, int& col0) {
  int i = blockIdx.x;
  int xcd = i & 7, slot = i >> 3;
  int col = slot & 3, tslot = slot >> 2;
  int rt = tslot * 8 + xcd;
  if (rt >= tiles[0]) return false;
  e = tiles[1 + 2 * rt];
  row0 = tiles[2 + 2 * rt];
  ne = counts[e];
  col0 = col * BN;
  return true;
}

// GEMM1: h[p, :] = relu( xb[tok(p), :] @ W1t[e]^T + b1[e] )   (bf16 out)
__global__ __launch_bounds__(256) void gemm1_kernel(
    const unsigned short* __restrict__ xb, const unsigned short* __restrict__ W1t,
    const float* __restrict__ b1, const int* __restrict__ lists,
    const int* __restrict__ counts, const int* __restrict__ tiles,
    unsigned short* __restrict__ h) {
  int e, ne, row0, col0;
  if (!decode_tile(tiles, counts, e, ne, row0, col0)) return;

  __shared__ unsigned short sA[BM * PITCH];
  __shared__ unsigned short sB[BN * PITCH];
  __shared__ int sTok[BM];

  int t = threadIdx.x;
  if (t < BM) {
    int r = row0 + t;
    sTok[t] = (r < ne) ? lists[e * NTOK + r] : -1;
  }
  __syncthreads();

  int arow = t >> 3, akq = t & 7;  // 32 rows/pass, 8 bf16 per lane
  const unsigned short* aSrc[4];
  const unsigned short* bSrc[4];
  int wOff[4];
#pragma unroll
  for (int j = 0; j < 4; ++j) {
    int p = sTok[j * 32 + arow];
    int tok = (p < 0) ? 0 : (p >> 1);
    aSrc[j] = xb + (size_t)tok * DDIM + akq * 8;
    int c = col0 + j * 32 + arow;
    bSrc[j] = W1t + ((size_t)e * HDIM + c) * DDIM + akq * 8;
    wOff[j] = (j * 32 + arow) * PITCH + akq * 8;
  }

  int wave = t >> 6, lane = t & 63;
  int wr = wave >> 1, wc = wave & 1;
  int aBase = (wr * 64 + (lane & 15)) * PITCH + (lane >> 4) * 8;
  int bBase = (wc * 64 + (lane & 15)) * PITCH + (lane >> 4) * 8;

  f32x4 acc[4][4];
#pragma unroll
  for (int m = 0; m < 4; ++m)
#pragma unroll
    for (int nn = 0; nn < 4; ++nn) acc[m][nn] = (f32x4)0.0f;

  us8 aReg[4], bReg[4];
#pragma unroll
  for (int j = 0; j < 4; ++j) aReg[j] = *(const us8*)(aSrc[j]);
#pragma unroll
  for (int j = 0; j < 4; ++j) bReg[j] = *(const us8*)(bSrc[j]);
#pragma unroll
  for (int j = 0; j < 4; ++j) *(us8*)&sA[wOff[j]] = aReg[j];
#pragma unroll
  for (int j = 0; j < 4; ++j) *(us8*)&sB[wOff[j]] = bReg[j];
  __syncthreads();

  const int NKT = DDIM / BK;  // 16
  for (int kt = 0; kt < NKT; ++kt) {
    if (kt + 1 < NKT) {
#pragma unroll
      for (int j = 0; j < 4; ++j) aReg[j] = *(const us8*)(aSrc[j] + (kt + 1) * BK);
#pragma unroll
      for (int j = 0; j < 4; ++j) bReg[j] = *(const us8*)(bSrc[j] + (kt + 1) * BK);
    }
#pragma unroll
    for (int ks = 0; ks < 2; ++ks) {
      bf16x8 af[4], bfr[4];
#pragma unroll
      for (int m = 0; m < 4; ++m)
        af[m] = *(const bf16x8*)&sA[aBase + m * 16 * PITCH + ks * 32];
#pragma unroll
      for (int nn = 0; nn < 4; ++nn)
        bfr[nn] = *(const bf16x8*)&sB[bBase + nn * 16 * PITCH + ks * 32];
#pragma unroll
      for (int m = 0; m < 4; ++m)
#pragma unroll
        for (int nn = 0; nn < 4; ++nn)
          acc[m][nn] = __builtin_amdgcn_mfma_f32_16x16x32_bf16(
              af[m], bfr[nn], acc[m][nn], 0, 0, 0);
    }
    __syncthreads();
    if (kt + 1 < NKT) {
#pragma unroll
      for (int j = 0; j < 4; ++j) *(us8*)&sA[wOff[j]] = aReg[j];
#pragma unroll
      for (int j = 0; j < 4; ++j) *(us8*)&sB[wOff[j]] = bReg[j];
    }
    __syncthreads();
  }

  int cBase = col0 + wc * 64 + (lane & 15);
  float b1c[4];
#pragma unroll
  for (int nn = 0; nn < 4; ++nn) b1c[nn] = b1[e * HDIM + cBase + nn * 16];
#pragma unroll
  for (int m = 0; m < 4; ++m) {
#pragma unroll
    for (int q = 0; q < 4; ++q) {
      int rloc = wr * 64 + m * 16 + (lane >> 4) * 4 + q;
      if (row0 + rloc < ne) {
        int p = sTok[rloc];
        unsigned short* hr = h + (size_t)p * HDIM;
#pragma unroll
        for (int nn = 0; nn < 4; ++nn) {
          float v = acc[m][nn][q] + b1c[nn];
          v = fmaxf(v, 0.0f);
          hr[cBase + nn * 16] = f2bf(v);
        }
      }
    }
  }
}

// GEMM2: out[tok(p), :] += w(p) * ( h[p, :] @ W2t[e]^T + b2[e] )
__global__ __launch_bounds__(256) void gemm2_kernel(
    const unsigned short* __restrict__ h, const unsigned short* __restrict__ W2t,
    const float* __restrict__ b2, const int* __restrict__ lists,
    const int* __restrict__ counts, const int* __restrict__ tiles,
    const float* __restrict__ wpair, float* __restrict__ out) {
  int e, ne, row0, col0;
  if (!decode_tile(tiles, counts, e, ne, row0, col0)) return;

  __shared__ unsigned short sA[BM * PITCH];
  __shared__ unsigned short sB[BN * PITCH];
  __shared__ int sTok[BM];
  __shared__ float sW[BM];

  int t = threadIdx.x;
  if (t < BM) {
    int r = row0 + t;
    int p = (r < ne) ? lists[e * NTOK + r] : -1;
    sTok[t] = p;
    sW[t] = (p >= 0) ? wpair[p] : 0.0f;
  }
  __syncthreads();

  int arow = t >> 3, akq = t & 7;
  const unsigned short* aSrc[4];
  const unsigned short* bSrc[4];
  int wOff[4];
#pragma unroll
  for (int j = 0; j < 4; ++j) {
    int p = sTok[j * 32 + arow];
    int pp = (p < 0) ? 0 : p;
    aSrc[j] = h + (size_t)pp * HDIM + akq * 8;
    int c = col0 + j * 32 + arow;
    bSrc[j] = W2t + ((size_t)e * CDIM + c) * HDIM + akq * 8;
    wOff[j] = (j * 32 + arow) * PITCH + akq * 8;
  }

  int wave = t >> 6, lane = t & 63;
  int wr = wave >> 1, wc = wave & 1;
  int aBase = (wr * 64 + (lane & 15)) * PITCH + (lane >> 4) * 8;
  int bBase = (wc * 64 + (lane & 15)) * PITCH + (lane >> 4) * 8;

  f32x4 acc[4][4];
#pragma unroll
  for (int m = 0; m < 4; ++m)
#pragma unroll
    for (int nn = 0; nn < 4; ++nn) acc[m][nn] = (f32x4)0.0f;

  us8 aReg[4], bReg[4];
#pragma unroll
  for (int j = 0; j < 4; ++j) aReg[j] = *(const us8*)(aSrc[j]);
#pragma unroll
  for (int j = 0; j < 4; ++j) bReg[j] = *(const us8*)(bSrc[j]);
#pragma unroll
  for (int j = 0; j < 4; ++j) *(us8*)&sA[wOff[j]] = aReg[j];
#pragma unroll
  for (int j = 0; j < 4; ++j) *(us8*)&sB[wOff[j]] = bReg[j];
  __syncthreads();

  const int NKT = HDIM / BK;  // 8
  for (int kt = 0; kt < NKT; ++kt) {
    if (kt + 1 < NKT) {
#pragma unroll
      for (int j = 0; j < 4; ++j) aReg[j] = *(const us8*)(aSrc[j] + (kt + 1) * BK);
#pragma unroll
      for (int j = 0; j < 4; ++j) bReg[j] = *(const us8*)(bSrc[j] + (kt + 1) * BK);
    }
#pragma unroll
    for (int ks = 0; ks < 2; ++ks) {
      bf16x8 af[4], bfr[4];
#pragma unroll
      for (int m = 0; m < 4; ++m)
        af[m] = *(const bf16x8*)&sA[aBase + m * 16 * PITCH + ks * 32];
#pragma unroll
      for (int nn = 0; nn < 4; ++nn)
        bfr[nn] = *(const bf16x8*)&sB[bBase + nn * 16 * PITCH + ks * 32];
#pragma unroll
      for (int m = 0; m < 4; ++m)
#pragma unroll
        for (int nn = 0; nn < 4; ++nn)
          acc[m][nn] = __builtin_amdgcn_mfma_f32_16x16x32_bf16(
              af[m], bfr[nn], acc[m][nn], 0, 0, 0);
    }
    __syncthreads();
    if (kt + 1 < NKT) {
#pragma unroll
      for (int j = 0; j < 4; ++j) *(us8*)&sA[wOff[j]] = aReg[j];
#pragma unroll
      for (int j = 0; j < 4; ++j) *(us8*)&sB[wOff[j]] = bReg[j];
    }
    __syncthreads();
  }

  int cBase = col0 + wc * 64 + (lane & 15);
  float b2c[4];
#pragma unroll
  for (int nn = 0; nn < 4; ++nn) b2c[nn] = b2[e * CDIM + cBase + nn * 16];
#pragma unroll
  for (int m = 0; m < 4; ++m) {
#pragma unroll
    for (int q = 0; q < 4; ++q) {
      int rloc = wr * 64 + m * 16 + (lane >> 4) * 4 + q;
      if (row0 + rloc < ne) {
        int p = sTok[rloc];
        float wgt = sW[rloc];
        int tok = p >> 1;
        float* orow = out + (size_t)tok * CDIM;
#pragma unroll
        for (int nn = 0; nn < 4; ++nn) {
          float v = (acc[m][nn][q] + b2c[nn]) * wgt;
          atomicAdd(&orow[cBase + nn * 16], v);
        }
      }
    }
  }
}

// ---------------------------------------------------------------------------
extern "C" void kernel_launch(void* const* d_in, const int* in_sizes, int n_in,
                              void* d_out, int out_size, void* d_ws, size_t ws_size,
                              hipStream_t stream) {
  const float* x  = (const float*)d_in[0];
  const float* W1 = (const float*)d_in[1];
  const float* b1 = (const float*)d_in[2];
  const float* W2 = (const float*)d_in[3];
  const float* b2 = (const float*)d_in[4];
  const float* Wg = (const float*)d_in[5];
  const float* bg = (const float*)d_in[6];
  float* out = (float*)d_out;
  char* ws = (char*)d_ws;

  // workspace layout (~77.4 MiB)
  int* counts = (int*)ws;                                    // 256 B
  float* wpair = (float*)(ws + 256);                         // 256 KiB
  int* sel = (int*)(ws + 256 + 262144);                      // 128 KiB
  int* lists = (int*)(ws + 256 + 262144 + 131072);           // 1 MiB
  int* tiles = (int*)(ws + 256 + 262144 + 131072 + 1048576); // 8 KiB
  unsigned short* W1t = (unsigned short*)(ws + 256 + 262144 + 131072 + 1048576 + 8192);
  unsigned short* W2t = W1t + (size_t)NEXP * HDIM * DDIM;    // +8 MiB
  unsigned short* hbuf = W2t + (size_t)NEXP * CDIM * HDIM;   // +4 MiB, hbuf 64 MiB

  // xb (bf16 x, 64 MiB) lives in d_out: dead before gemm2 zeroes/uses it.
  unsigned short* xb = (unsigned short*)d_out;

  hipLaunchKernelGGL(transpose_bf16_kernel, dim3(HDIM / 32, DDIM / 32, NEXP),
                     dim3(32, 8), 0, stream, W1, W1t, DDIM, HDIM);
  hipLaunchKernelGGL(transpose_bf16_kernel, dim3(CDIM / 32, HDIM / 32, NEXP),
                     dim3(32, 8), 0, stream, W2, W2t, HDIM, CDIM);
  hipLaunchKernelGGL(gate_logits_kernel, dim3(NTOK / 16), dim3(256), 0, stream,
                     x, Wg, bg, sel, wpair, xb);
  hipLaunchKernelGGL(build_lists_kernel, dim3(NEXP), dim3(1024), 0, stream,
                     sel, counts, lists);
  hipLaunchKernelGGL(make_tiles_kernel, dim3(1), dim3(256), 0, stream,
                     counts, tiles);
  hipLaunchKernelGGL(gemm1_kernel, dim3((MAXTILE / 8) * 4 * 8), dim3(256),
                     0, stream, xb, W1t, b1, lists, counts, tiles, hbuf);
  hipMemsetAsync(d_out, 0, (size_t)out_size * sizeof(float), stream);
  hipLaunchKernelGGL(gemm2_kernel, dim3((MAXTILE / 8) * 4 * 8), dim3(256),
                     0, stream, hbuf, W2t, b2, lists, counts, tiles, wpair, out);
}

// Round 5
// 360.802 us; speedup vs baseline: 3.1623x; 1.2580x over previous
//
#include <hip/hip_runtime.h>

// Problem constants
#define NTOK 32768
#define DDIM 1024
#define HDIM 512
#define CDIM 512
#define NEXP 8

#define BM 128
#define BN 128
#define BK 64
#define PITCH 72
#define MAXTILE 520   // sum ceil(ne/128) <= 512 + 8

typedef __attribute__((ext_vector_type(8))) __bf16 bf16x8;
typedef __attribute__((ext_vector_type(4))) float f32x4;
typedef __attribute__((ext_vector_type(4))) unsigned short us4;
typedef __attribute__((ext_vector_type(8))) unsigned short us8;

static __device__ __forceinline__ unsigned short f2bf(float f) {
  union { float f; unsigned u; } v; v.f = f;
  unsigned u = v.u;
  u += 0x7FFFu + ((u >> 16) & 1u);   // RNE round to bf16
  return (unsigned short)(u >> 16);
}

// ---------------------------------------------------------------------------
// Transpose [E][R][Cc] fp32 -> [E][Cc][R] bf16
// ---------------------------------------------------------------------------
__global__ __launch_bounds__(256) void transpose_bf16_kernel(
    const float* __restrict__ in, unsigned short* __restrict__ out,
    int R, int Cc) {
  __shared__ float tile[32][33];
  int e = blockIdx.z;
  int c0 = blockIdx.x * 32, r0 = blockIdx.y * 32;
  const float* src = in + (size_t)e * R * Cc;
  unsigned short* dst = out + (size_t)e * R * Cc;
  int tx = threadIdx.x, ty = threadIdx.y;  // (32, 8)
#pragma unroll
  for (int i = 0; i < 32; i += 8)
    tile[ty + i][tx] = src[(size_t)(r0 + ty + i) * Cc + (c0 + tx)];
  __syncthreads();
#pragma unroll
  for (int i = 0; i < 32; i += 8)
    dst[(size_t)(c0 + ty + i) * R + (r0 + tx)] = f2bf(tile[tx][ty + i]);
}

// ---------------------------------------------------------------------------
// Gate v4: scalar f32-Kahan logits + f64 combine, fused bf16-x emission.
// 1024 blocks x 4 waves; each wave owns 8 rows. Lane (g,e): g=lane>>3 owns
// d in [128g,128g+128) for expert e=lane&7. Wave-private x slab in LDS
// (skewed +4 words per 128-block): wg reads 2-way (free), x reads broadcast.
// No atomics; no barriers in the row loop.
// ---------------------------------------------------------------------------
#define GWPITCH 1064   // wg_lds expert pitch (words): %32==8, %4==0, >=1052
#define XSLOT 1056     // per-wave x slab words (max skewed idx 1051)

__global__ __launch_bounds__(256) void gate_kernel(
    const float* __restrict__ x, const float* __restrict__ Wg,
    const float* __restrict__ bg, int* __restrict__ sel,
    float* __restrict__ wpair, unsigned short* __restrict__ xb) {
  __shared__ float wg_lds[NEXP * GWPITCH];   // ~34 KB, [e][d + 4*(d>>7)]
  __shared__ float xs[4][XSLOT];             // ~16.5 KB, per-wave slab

  int t = threadIdx.x;
  // stage Wg [d][e] -> wg_lds[e][skew(d)]
  for (int i = t; i < DDIM * NEXP / 4; i += 256) {
    f32x4 v = *(const f32x4*)(Wg + (size_t)i * 4);
    int d = i >> 1;
    int e0 = (i & 1) * 4;
    int dsk = d + 4 * (d >> 7);
#pragma unroll
    for (int z = 0; z < 4; ++z)
      wg_lds[(e0 + z) * GWPITCH + dsk] = v[z];
  }
  __syncthreads();

  int wave = t >> 6, lane = t & 63;
  int g = lane >> 3, e = lane & 7;
  float* xslab = xs[wave];
  const float* wgrow = wg_lds + e * GWPITCH + g * 132;  // 128g + 4g skew
  const float* xsg = xslab + g * 132;
  double bge = (double)bg[e];

  int n0 = blockIdx.x * 32 + wave * 8;
  f32x4 ld[4], ldn[4];
  {
    const f32x4* xrow = (const f32x4*)(x + (size_t)n0 * DDIM);
#pragma unroll
    for (int j = 0; j < 4; ++j) ld[j] = xrow[j * 64 + lane];
  }

#pragma unroll 1
  for (int r = 0; r < 8; ++r) {
    int n = n0 + r;
    // commit row r: skewed slab + xb (bf16) from the same registers
    unsigned short* xbr = xb + (size_t)n * DDIM;
#pragma unroll
    for (int j = 0; j < 4; ++j) {
      int d0 = j * 256 + lane * 4;
      *(f32x4*)&xslab[d0 + 4 * (d0 >> 7)] = ld[j];
      us4 o;
#pragma unroll
      for (int z = 0; z < 4; ++z) o[z] = f2bf(ld[j][z]);
      *(us4*)&xbr[d0] = o;
    }
    // prefetch next row (hides HBM under compute)
    if (r < 7) {
      const f32x4* xr2 = (const f32x4*)(x + (size_t)(n + 1) * DDIM);
#pragma unroll
      for (int j = 0; j < 4; ++j) ldn[j] = xr2[j * 64 + lane];
    }
    // partial logit for (row n, expert e) over d in [128g, 128g+128)
    // two interleaved f32 Kahan chains (z even / z odd) for ILP
    float s0 = 0.0f, c0 = 0.0f, s1 = 0.0f, c1 = 0.0f;
#pragma unroll
    for (int k = 0; k < 32; ++k) {
      f32x4 xv = *(const f32x4*)&xsg[4 * k];
      f32x4 wv = *(const f32x4*)&wgrow[4 * k];
#pragma unroll
      for (int z = 0; z < 4; z += 2) {
        float p0 = xv[z] * wv[z];
        float y0 = p0 - c0;
        float t0 = s0 + y0;
        c0 = (t0 - s0) - y0;
        s0 = t0;
        float p1 = xv[z + 1] * wv[z + 1];
        float y1 = p1 - c1;
        float t1 = s1 + y1;
        c1 = (t1 - s1) - y1;
        s1 = t1;
      }
    }
    double p = ((double)s0 + (double)c0) + ((double)s1 + (double)c1);
    p += __shfl_xor(p, 8, 64);
    p += __shfl_xor(p, 16, 64);
    p += __shfl_xor(p, 32, 64);
    double mylg = p + bge;   // lanes 0..7 (and replicas) hold logit[e]
    // gather all 8 logits to every lane, then lane 0 writes top-2
    double lg[NEXP];
#pragma unroll
    for (int ee = 0; ee < NEXP; ++ee) lg[ee] = __shfl(mylg, ee, 64);
    if (lane == 0) {
      int e0i = 0;
#pragma unroll
      for (int ee = 1; ee < NEXP; ++ee) if (lg[ee] > lg[e0i]) e0i = ee;  // earliest on tie
      int e1i = (e0i == 0) ? 1 : 0;
#pragma unroll
      for (int ee = 0; ee < NEXP; ++ee)
        if (ee != e0i && lg[ee] > lg[e1i]) e1i = ee;                     // earliest on tie
      float w1 = 1.0f / (1.0f + expf((float)(lg[e0i] - lg[e1i])));
      float w0 = 1.0f - w1;
      sel[n] = e0i | (e1i << 4);
      wpair[n * 2] = w0;
      wpair[n * 2 + 1] = w1;
    }
#pragma unroll
    for (int j = 0; j < 4; ++j) ld[j] = ldn[j];
  }
}

// ---------------------------------------------------------------------------
// Build per-expert pair lists via deterministic block-wide prefix scan.
// grid = NEXP blocks, 1024 threads; thread t owns rows [t*32, t*32+32).
// ---------------------------------------------------------------------------
__global__ __launch_bounds__(1024) void build_lists_kernel(
    const int* __restrict__ sel, int* __restrict__ counts,
    int* __restrict__ lists) {
  int e = blockIdx.x;
  int t = threadIdx.x;
  __shared__ int sc[1024];
  int base = t * (NTOK / 1024);
  int cnt = 0;
#pragma unroll
  for (int i = 0; i < NTOK / 1024; ++i) {
    int s = sel[base + i];
    cnt += ((s & 15) == e) || (((s >> 4) & 15) == e);
  }
  sc[t] = cnt;
  __syncthreads();
  for (int d = 1; d < 1024; d <<= 1) {
    int v = (t >= d) ? sc[t - d] : 0;
    __syncthreads();
    sc[t] += v;
    __syncthreads();
  }
  int off = sc[t] - cnt;
#pragma unroll
  for (int i = 0; i < NTOK / 1024; ++i) {
    int s = sel[base + i];
    if ((s & 15) == e)
      lists[e * NTOK + off++] = (base + i) * 2;
    else if (((s >> 4) & 15) == e)
      lists[e * NTOK + off++] = (base + i) * 2 + 1;
  }
  if (t == 1023) counts[e] = sc[1023];
}

// ---------------------------------------------------------------------------
// Tile table: tiles[0]=ntiles; tiles[1+2t]=expert, tiles[2+2t]=row0.
// ---------------------------------------------------------------------------
__global__ __launch_bounds__(256) void make_tiles_kernel(
    const int* __restrict__ counts, int* __restrict__ tiles) {
  __shared__ int off[NEXP + 1];
  int t = threadIdx.x;
  if (t == 0) {
    int s = 0;
    for (int e = 0; e < NEXP; ++e) { off[e] = s; s += (counts[e] + BM - 1) / BM; }
    off[NEXP] = s;
    tiles[0] = s;
  }
  __syncthreads();
  for (int e = 0; e < NEXP; ++e) {
    int base = off[e], cnt = off[e + 1] - off[e];
    for (int k = t; k < cnt; k += 256) {
      tiles[1 + 2 * (base + k)] = e;
      tiles[2 + 2 * (base + k)] = k * BM;
    }
  }
}

// ---------------------------------------------------------------------------
// XCD-chunked decode: grid = 65*4*8 = 2080 flat blocks.
// col-blocks of one row-tile -> ids i, i+8, i+16, i+24 (same XCD).
// ---------------------------------------------------------------------------
static __device__ __forceinline__ bool decode_tile(
    const int* tiles, const int* counts, int& e, int& ne, int& row0, int& col0) {
  int i = blockIdx.x;
  int xcd = i & 7, slot = i >> 3;
  int col = slot & 3, tslot = slot >> 2;
  int rt = tslot * 8 + xcd;
  if (rt >= tiles[0]) return false;
  e = tiles[1 + 2 * rt];
  row0 = tiles[2 + 2 * rt];
  ne = counts[e];
  col0 = col * BN;
  return true;
}

// GEMM1: h[p, :] = relu( xb[tok(p), :] @ W1t[e]^T + b1[e] )   (bf16 out)
__global__ __launch_bounds__(256) void gemm1_kernel(
    const unsigned short* __restrict__ xb, const unsigned short* __restrict__ W1t,
    const float* __restrict__ b1, const int* __restrict__ lists,
    const int* __restrict__ counts, const int* __restrict__ tiles,
    unsigned short* __restrict__ h) {
  int e, ne, row0, col0;
  if (!decode_tile(tiles, counts, e, ne, row0, col0)) return;

  __shared__ unsigned short sA[BM * PITCH];
  __shared__ unsigned short sB[BN * PITCH];
  __shared__ int sTok[BM];

  int t = threadIdx.x;
  if (t < BM) {
    int r = row0 + t;
    sTok[t] = (r < ne) ? lists[e * NTOK + r] : -1;
  }
  __syncthreads();

  int arow = t >> 3, akq = t & 7;  // 32 rows/pass, 8 bf16 per lane
  const unsigned short* aSrc[4];
  const unsigned short* bSrc[4];
  int wOff[4];
#pragma unroll
  for (int j = 0; j < 4; ++j) {
    int p = sTok[j * 32 + arow];
    int tok = (p < 0) ? 0 : (p >> 1);
    aSrc[j] = xb + (size_t)tok * DDIM + akq * 8;
    int c = col0 + j * 32 + arow;
    bSrc[j] = W1t + ((size_t)e * HDIM + c) * DDIM + akq * 8;
    wOff[j] = (j * 32 + arow) * PITCH + akq * 8;
  }

  int wave = t >> 6, lane = t & 63;
  int wr = wave >> 1, wc = wave & 1;
  int aBase = (wr * 64 + (lane & 15)) * PITCH + (lane >> 4) * 8;
  int bBase = (wc * 64 + (lane & 15)) * PITCH + (lane >> 4) * 8;

  f32x4 acc[4][4];
#pragma unroll
  for (int m = 0; m < 4; ++m)
#pragma unroll
    for (int nn = 0; nn < 4; ++nn) acc[m][nn] = (f32x4)0.0f;

  us8 aReg[4], bReg[4];
#pragma unroll
  for (int j = 0; j < 4; ++j) aReg[j] = *(const us8*)(aSrc[j]);
#pragma unroll
  for (int j = 0; j < 4; ++j) bReg[j] = *(const us8*)(bSrc[j]);
#pragma unroll
  for (int j = 0; j < 4; ++j) *(us8*)&sA[wOff[j]] = aReg[j];
#pragma unroll
  for (int j = 0; j < 4; ++j) *(us8*)&sB[wOff[j]] = bReg[j];
  __syncthreads();

  const int NKT = DDIM / BK;  // 16
  for (int kt = 0; kt < NKT; ++kt) {
    if (kt + 1 < NKT) {
#pragma unroll
      for (int j = 0; j < 4; ++j) aReg[j] = *(const us8*)(aSrc[j] + (kt + 1) * BK);
#pragma unroll
      for (int j = 0; j < 4; ++j) bReg[j] = *(const us8*)(bSrc[j] + (kt + 1) * BK);
    }
#pragma unroll
    for (int ks = 0; ks < 2; ++ks) {
      bf16x8 af[4], bfr[4];
#pragma unroll
      for (int m = 0; m < 4; ++m)
        af[m] = *(const bf16x8*)&sA[aBase + m * 16 * PITCH + ks * 32];
#pragma unroll
      for (int nn = 0; nn < 4; ++nn)
        bfr[nn] = *(const bf16x8*)&sB[bBase + nn * 16 * PITCH + ks * 32];
#pragma unroll
      for (int m = 0; m < 4; ++m)
#pragma unroll
        for (int nn = 0; nn < 4; ++nn)
          acc[m][nn] = __builtin_amdgcn_mfma_f32_16x16x32_bf16(
              af[m], bfr[nn], acc[m][nn], 0, 0, 0);
    }
    __syncthreads();
    if (kt + 1 < NKT) {
#pragma unroll
      for (int j = 0; j < 4; ++j) *(us8*)&sA[wOff[j]] = aReg[j];
#pragma unroll
      for (int j = 0; j < 4; ++j) *(us8*)&sB[wOff[j]] = bReg[j];
    }
    __syncthreads();
  }

  int cBase = col0 + wc * 64 + (lane & 15);
  float b1c[4];
#pragma unroll
  for (int nn = 0; nn < 4; ++nn) b1c[nn] = b1[e * HDIM + cBase + nn * 16];
#pragma unroll
  for (int m = 0; m < 4; ++m) {
#pragma unroll
    for (int q = 0; q < 4; ++q) {
      int rloc = wr * 64 + m * 16 + (lane >> 4) * 4 + q;
      if (row0 + rloc < ne) {
        int p = sTok[rloc];
        unsigned short* hr = h + (size_t)p * HDIM;
#pragma unroll
        for (int nn = 0; nn < 4; ++nn) {
          float v = acc[m][nn][q] + b1c[nn];
          v = fmaxf(v, 0.0f);
          hr[cBase + nn * 16] = f2bf(v);
        }
      }
    }
  }
}

// GEMM2: out[tok(p), :] += w(p) * ( h[p, :] @ W2t[e]^T + b2[e] )
__global__ __launch_bounds__(256) void gemm2_kernel(
    const unsigned short* __restrict__ h, const unsigned short* __restrict__ W2t,
    const float* __restrict__ b2, const int* __restrict__ lists,
    const int* __restrict__ counts, const int* __restrict__ tiles,
    const float* __restrict__ wpair, float* __restrict__ out) {
  int e, ne, row0, col0;
  if (!decode_tile(tiles, counts, e, ne, row0, col0)) return;

  __shared__ unsigned short sA[BM * PITCH];
  __shared__ unsigned short sB[BN * PITCH];
  __shared__ int sTok[BM];
  __shared__ float sW[BM];

  int t = threadIdx.x;
  if (t < BM) {
    int r = row0 + t;
    int p = (r < ne) ? lists[e * NTOK + r] : -1;
    sTok[t] = p;
    sW[t] = (p >= 0) ? wpair[p] : 0.0f;
  }
  __syncthreads();

  int arow = t >> 3, akq = t & 7;
  const unsigned short* aSrc[4];
  const unsigned short* bSrc[4];
  int wOff[4];
#pragma unroll
  for (int j = 0; j < 4; ++j) {
    int p = sTok[j * 32 + arow];
    int pp = (p < 0) ? 0 : p;
    aSrc[j] = h + (size_t)pp * HDIM + akq * 8;
    int c = col0 + j * 32 + arow;
    bSrc[j] = W2t + ((size_t)e * CDIM + c) * HDIM + akq * 8;
    wOff[j] = (j * 32 + arow) * PITCH + akq * 8;
  }

  int wave = t >> 6, lane = t & 63;
  int wr = wave >> 1, wc = wave & 1;
  int aBase = (wr * 64 + (lane & 15)) * PITCH + (lane >> 4) * 8;
  int bBase = (wc * 64 + (lane & 15)) * PITCH + (lane >> 4) * 8;

  f32x4 acc[4][4];
#pragma unroll
  for (int m = 0; m < 4; ++m)
#pragma unroll
    for (int nn = 0; nn < 4; ++nn) acc[m][nn] = (f32x4)0.0f;

  us8 aReg[4], bReg[4];
#pragma unroll
  for (int j = 0; j < 4; ++j) aReg[j] = *(const us8*)(aSrc[j]);
#pragma unroll
  for (int j = 0; j < 4; ++j) bReg[j] = *(const us8*)(bSrc[j]);
#pragma unroll
  for (int j = 0; j < 4; ++j) *(us8*)&sA[wOff[j]] = aReg[j];
#pragma unroll
  for (int j = 0; j < 4; ++j) *(us8*)&sB[wOff[j]] = bReg[j];
  __syncthreads();

  const int NKT = HDIM / BK;  // 8
  for (int kt = 0; kt < NKT; ++kt) {
    if (kt + 1 < NKT) {
#pragma unroll
      for (int j = 0; j < 4; ++j) aReg[j] = *(const us8*)(aSrc[j] + (kt + 1) * BK);
#pragma unroll
      for (int j = 0; j < 4; ++j) bReg[j] = *(const us8*)(bSrc[j] + (kt + 1) * BK);
    }
#pragma unroll
    for (int ks = 0; ks < 2; ++ks) {
      bf16x8 af[4], bfr[4];
#pragma unroll
      for (int m = 0; m < 4; ++m)
        af[m] = *(const bf16x8*)&sA[aBase + m * 16 * PITCH + ks * 32];
#pragma unroll
      for (int nn = 0; nn < 4; ++nn)
        bfr[nn] = *(const bf16x8*)&sB[bBase + nn * 16 * PITCH + ks * 32];
#pragma unroll
      for (int m = 0; m < 4; ++m)
#pragma unroll
        for (int nn = 0; nn < 4; ++nn)
          acc[m][nn] = __builtin_amdgcn_mfma_f32_16x16x32_bf16(
              af[m], bfr[nn], acc[m][nn], 0, 0, 0);
    }
    __syncthreads();
    if (kt + 1 < NKT) {
#pragma unroll
      for (int j = 0; j < 4; ++j) *(us8*)&sA[wOff[j]] = aReg[j];
#pragma unroll
      for (int j = 0; j < 4; ++j) *(us8*)&sB[wOff[j]] = bReg[j];
    }
    __syncthreads();
  }

  int cBase = col0 + wc * 64 + (lane & 15);
  float b2c[4];
#pragma unroll
  for (int nn = 0; nn < 4; ++nn) b2c[nn] = b2[e * CDIM + cBase + nn * 16];
#pragma unroll
  for (int m = 0; m < 4; ++m) {
#pragma unroll
    for (int q = 0; q < 4; ++q) {
      int rloc = wr * 64 + m * 16 + (lane >> 4) * 4 + q;
      if (row0 + rloc < ne) {
        int p = sTok[rloc];
        float wgt = sW[rloc];
        int tok = p >> 1;
        float* orow = out + (size_t)tok * CDIM;
#pragma unroll
        for (int nn = 0; nn < 4; ++nn) {
          float v = (acc[m][nn][q] + b2c[nn]) * wgt;
          atomicAdd(&orow[cBase + nn * 16], v);
        }
      }
    }
  }
}

// ---------------------------------------------------------------------------
extern "C" void kernel_launch(void* const* d_in, const int* in_sizes, int n_in,
                              void* d_out, int out_size, void* d_ws, size_t ws_size,
                              hipStream_t stream) {
  const float* x  = (const float*)d_in[0];
  const float* W1 = (const float*)d_in[1];
  const float* b1 = (const float*)d_in[2];
  const float* W2 = (const float*)d_in[3];
  const float* b2 = (const float*)d_in[4];
  const float* Wg = (const float*)d_in[5];
  const float* bg = (const float*)d_in[6];
  float* out = (float*)d_out;
  char* ws = (char*)d_ws;

  // workspace layout (~77.4 MiB)
  int* counts = (int*)ws;                                    // 256 B
  float* wpair = (float*)(ws + 256);                         // 256 KiB
  int* sel = (int*)(ws + 256 + 262144);                      // 128 KiB
  int* lists = (int*)(ws + 256 + 262144 + 131072);           // 1 MiB
  int* tiles = (int*)(ws + 256 + 262144 + 131072 + 1048576); // 8 KiB
  unsigned short* W1t = (unsigned short*)(ws + 256 + 262144 + 131072 + 1048576 + 8192);
  unsigned short* W2t = W1t + (size_t)NEXP * HDIM * DDIM;    // +8 MiB
  unsigned short* hbuf = W2t + (size_t)NEXP * CDIM * HDIM;   // +4 MiB, hbuf 64 MiB

  // xb (bf16 x, 64 MiB) lives in d_out: dead before gemm2 zeroes/uses it.
  unsigned short* xb = (unsigned short*)d_out;

  hipLaunchKernelGGL(transpose_bf16_kernel, dim3(HDIM / 32, DDIM / 32, NEXP),
                     dim3(32, 8), 0, stream, W1, W1t, DDIM, HDIM);
  hipLaunchKernelGGL(transpose_bf16_kernel, dim3(CDIM / 32, HDIM / 32, NEXP),
                     dim3(32, 8), 0, stream, W2, W2t, HDIM, CDIM);
  hipLaunchKernelGGL(gate_kernel, dim3(NTOK / 32), dim3(256), 0, stream,
                     x, Wg, bg, sel, wpair, xb);
  hipLaunchKernelGGL(build_lists_kernel, dim3(NEXP), dim3(1024), 0, stream,
                     sel, counts, lists);
  hipLaunchKernelGGL(make_tiles_kernel, dim3(1), dim3(256), 0, stream,
                     counts, tiles);
  hipLaunchKernelGGL(gemm1_kernel, dim3((MAXTILE / 8) * 4 * 8), dim3(256),
                     0, stream, xb, W1t, b1, lists, counts, tiles, hbuf);
  hipMemsetAsync(d_out, 0, (size_t)out_size * sizeof(float), stream);
  hipLaunchKernelGGL(gemm2_kernel, dim3((MAXTILE / 8) * 4 * 8), dim3(256),
                     0, stream, hbuf, W2t, b2, lists, counts, tiles, wpair, out);
}

// Round 6
// 297.020 us; speedup vs baseline: 3.8414x; 1.2147x over previous
//
#include <hip/hip_runtime.h>

// Problem constants
#define NTOK 32768
#define DDIM 1024
#define HDIM 512
#define CDIM 512
#define NEXP 8

#define BM 128
#define BN 128
#define BK 64
#define PITCH 72
#define MAXTILE 520   // sum ceil(ne/128) <= 512 + 8

typedef __attribute__((ext_vector_type(8))) __bf16 bf16x8;
typedef __attribute__((ext_vector_type(4))) float f32x4;
typedef __attribute__((ext_vector_type(4))) unsigned short us4;
typedef __attribute__((ext_vector_type(8))) unsigned short us8;

static __device__ __forceinline__ unsigned short f2bf(float f) {
  union { float f; unsigned u; } v; v.f = f;
  unsigned u = v.u;
  u += 0x7FFFu + ((u >> 16) & 1u);   // RNE round to bf16
  return (unsigned short)(u >> 16);
}

static __device__ __forceinline__ float bf2f(unsigned short s) {
  union { unsigned u; float f; } v;
  v.u = ((unsigned)s) << 16;
  return v.f;
}

// ---------------------------------------------------------------------------
// Transpose [E][R][Cc] fp32 -> [E][Cc][R] bf16
// ---------------------------------------------------------------------------
__global__ __launch_bounds__(256) void transpose_bf16_kernel(
    const float* __restrict__ in, unsigned short* __restrict__ out,
    int R, int Cc) {
  __shared__ float tile[32][33];
  int e = blockIdx.z;
  int c0 = blockIdx.x * 32, r0 = blockIdx.y * 32;
  const float* src = in + (size_t)e * R * Cc;
  unsigned short* dst = out + (size_t)e * R * Cc;
  int tx = threadIdx.x, ty = threadIdx.y;  // (32, 8)
#pragma unroll
  for (int i = 0; i < 32; i += 8)
    tile[ty + i][tx] = src[(size_t)(r0 + ty + i) * Cc + (c0 + tx)];
  __syncthreads();
#pragma unroll
  for (int i = 0; i < 32; i += 8)
    dst[(size_t)(c0 + ty + i) * R + (r0 + tx)] = f2bf(tile[tx][ty + i]);
}

// ---------------------------------------------------------------------------
// Gate v4: scalar f32-Kahan logits + f64 combine, fused bf16-x emission.
// 1024 blocks x 4 waves; each wave owns 8 rows. Lane (g,e): g=lane>>3 owns
// d in [128g,128g+128) for expert e=lane&7. Wave-private x slab in LDS
// (skewed +4 words per 128-block). No atomics; no barriers in the row loop.
// ---------------------------------------------------------------------------
#define GWPITCH 1064   // wg_lds expert pitch (words)
#define XSLOT 1056     // per-wave x slab words

__global__ __launch_bounds__(256) void gate_kernel(
    const float* __restrict__ x, const float* __restrict__ Wg,
    const float* __restrict__ bg, int* __restrict__ sel,
    float* __restrict__ wpair, unsigned short* __restrict__ xb) {
  __shared__ float wg_lds[NEXP * GWPITCH];   // ~34 KB, [e][d + 4*(d>>7)]
  __shared__ float xs[4][XSLOT];             // ~16.5 KB, per-wave slab

  int t = threadIdx.x;
  for (int i = t; i < DDIM * NEXP / 4; i += 256) {
    f32x4 v = *(const f32x4*)(Wg + (size_t)i * 4);
    int d = i >> 1;
    int e0 = (i & 1) * 4;
    int dsk = d + 4 * (d >> 7);
#pragma unroll
    for (int z = 0; z < 4; ++z)
      wg_lds[(e0 + z) * GWPITCH + dsk] = v[z];
  }
  __syncthreads();

  int wave = t >> 6, lane = t & 63;
  int g = lane >> 3, e = lane & 7;
  float* xslab = xs[wave];
  const float* wgrow = wg_lds + e * GWPITCH + g * 132;  // 128g + 4g skew
  const float* xsg = xslab + g * 132;
  double bge = (double)bg[e];

  int n0 = blockIdx.x * 32 + wave * 8;
  f32x4 ld[4], ldn[4];
  {
    const f32x4* xrow = (const f32x4*)(x + (size_t)n0 * DDIM);
#pragma unroll
    for (int j = 0; j < 4; ++j) ld[j] = xrow[j * 64 + lane];
  }

#pragma unroll 1
  for (int r = 0; r < 8; ++r) {
    int n = n0 + r;
    unsigned short* xbr = xb + (size_t)n * DDIM;
#pragma unroll
    for (int j = 0; j < 4; ++j) {
      int d0 = j * 256 + lane * 4;
      *(f32x4*)&xslab[d0 + 4 * (d0 >> 7)] = ld[j];
      us4 o;
#pragma unroll
      for (int z = 0; z < 4; ++z) o[z] = f2bf(ld[j][z]);
      *(us4*)&xbr[d0] = o;
    }
    if (r < 7) {
      const f32x4* xr2 = (const f32x4*)(x + (size_t)(n + 1) * DDIM);
#pragma unroll
      for (int j = 0; j < 4; ++j) ldn[j] = xr2[j * 64 + lane];
    }
    float s0 = 0.0f, c0 = 0.0f, s1 = 0.0f, c1 = 0.0f;
#pragma unroll
    for (int k = 0; k < 32; ++k) {
      f32x4 xv = *(const f32x4*)&xsg[4 * k];
      f32x4 wv = *(const f32x4*)&wgrow[4 * k];
#pragma unroll
      for (int z = 0; z < 4; z += 2) {
        float p0 = xv[z] * wv[z];
        float y0 = p0 - c0;
        float t0 = s0 + y0;
        c0 = (t0 - s0) - y0;
        s0 = t0;
        float p1 = xv[z + 1] * wv[z + 1];
        float y1 = p1 - c1;
        float t1 = s1 + y1;
        c1 = (t1 - s1) - y1;
        s1 = t1;
      }
    }
    double p = ((double)s0 + (double)c0) + ((double)s1 + (double)c1);
    p += __shfl_xor(p, 8, 64);
    p += __shfl_xor(p, 16, 64);
    p += __shfl_xor(p, 32, 64);
    double mylg = p + bge;
    double lg[NEXP];
#pragma unroll
    for (int ee = 0; ee < NEXP; ++ee) lg[ee] = __shfl(mylg, ee, 64);
    if (lane == 0) {
      int e0i = 0;
#pragma unroll
      for (int ee = 1; ee < NEXP; ++ee) if (lg[ee] > lg[e0i]) e0i = ee;  // earliest on tie
      int e1i = (e0i == 0) ? 1 : 0;
#pragma unroll
      for (int ee = 0; ee < NEXP; ++ee)
        if (ee != e0i && lg[ee] > lg[e1i]) e1i = ee;                     // earliest on tie
      float w1 = 1.0f / (1.0f + expf((float)(lg[e0i] - lg[e1i])));
      float w0 = 1.0f - w1;
      sel[n] = e0i | (e1i << 4);
      wpair[n * 2] = w0;
      wpair[n * 2 + 1] = w1;
    }
#pragma unroll
    for (int j = 0; j < 4; ++j) ld[j] = ldn[j];
  }
}

// ---------------------------------------------------------------------------
// Build per-expert pair lists via deterministic block-wide prefix scan.
// ---------------------------------------------------------------------------
__global__ __launch_bounds__(1024) void build_lists_kernel(
    const int* __restrict__ sel, int* __restrict__ counts,
    int* __restrict__ lists) {
  int e = blockIdx.x;
  int t = threadIdx.x;
  __shared__ int sc[1024];
  int base = t * (NTOK / 1024);
  int cnt = 0;
#pragma unroll
  for (int i = 0; i < NTOK / 1024; ++i) {
    int s = sel[base + i];
    cnt += ((s & 15) == e) || (((s >> 4) & 15) == e);
  }
  sc[t] = cnt;
  __syncthreads();
  for (int d = 1; d < 1024; d <<= 1) {
    int v = (t >= d) ? sc[t - d] : 0;
    __syncthreads();
    sc[t] += v;
    __syncthreads();
  }
  int off = sc[t] - cnt;
#pragma unroll
  for (int i = 0; i < NTOK / 1024; ++i) {
    int s = sel[base + i];
    if ((s & 15) == e)
      lists[e * NTOK + off++] = (base + i) * 2;
    else if (((s >> 4) & 15) == e)
      lists[e * NTOK + off++] = (base + i) * 2 + 1;
  }
  if (t == 1023) counts[e] = sc[1023];
}

// ---------------------------------------------------------------------------
// Tile table: tiles[0]=ntiles; tiles[1+2t]=expert, tiles[2+2t]=row0.
// ---------------------------------------------------------------------------
__global__ __launch_bounds__(256) void make_tiles_kernel(
    const int* __restrict__ counts, int* __restrict__ tiles) {
  __shared__ int off[NEXP + 1];
  int t = threadIdx.x;
  if (t == 0) {
    int s = 0;
    for (int e = 0; e < NEXP; ++e) { off[e] = s; s += (counts[e] + BM - 1) / BM; }
    off[NEXP] = s;
    tiles[0] = s;
  }
  __syncthreads();
  for (int e = 0; e < NEXP; ++e) {
    int base = off[e], cnt = off[e + 1] - off[e];
    for (int k = t; k < cnt; k += 256) {
      tiles[1 + 2 * (base + k)] = e;
      tiles[2 + 2 * (base + k)] = k * BM;
    }
  }
}

// ---------------------------------------------------------------------------
// XCD-chunked decode: grid = 65*4*8 = 2080 flat blocks.
// ---------------------------------------------------------------------------
static __device__ __forceinline__ bool decode_tile(
    const int* tiles, const int* counts, int& e, int& ne, int& row0, int& col0) {
  int i = blockIdx.x;
  int xcd = i & 7, slot = i >> 3;
  int col = slot & 3, tslot = slot >> 2;
  int rt = tslot * 8 + xcd;
  if (rt >= tiles[0]) return false;
  e = tiles[1 + 2 * rt];
  row0 = tiles[2 + 2 * rt];
  ne = counts[e];
  col0 = col * BN;
  return true;
}

// GEMM1: h[p, :] = relu( xb[tok(p), :] @ W1t[e]^T + b1[e] )   (bf16 out)
__global__ __launch_bounds__(256) void gemm1_kernel(
    const unsigned short* __restrict__ xb, const unsigned short* __restrict__ W1t,
    const float* __restrict__ b1, const int* __restrict__ lists,
    const int* __restrict__ counts, const int* __restrict__ tiles,
    unsigned short* __restrict__ h) {
  int e, ne, row0, col0;
  if (!decode_tile(tiles, counts, e, ne, row0, col0)) return;

  __shared__ unsigned short sA[BM * PITCH];
  __shared__ unsigned short sB[BN * PITCH];
  __shared__ int sTok[BM];

  int t = threadIdx.x;
  if (t < BM) {
    int r = row0 + t;
    sTok[t] = (r < ne) ? lists[e * NTOK + r] : -1;
  }
  __syncthreads();

  int arow = t >> 3, akq = t & 7;  // 32 rows/pass, 8 bf16 per lane
  const unsigned short* aSrc[4];
  const unsigned short* bSrc[4];
  int wOff[4];
#pragma unroll
  for (int j = 0; j < 4; ++j) {
    int p = sTok[j * 32 + arow];
    int tok = (p < 0) ? 0 : (p >> 1);
    aSrc[j] = xb + (size_t)tok * DDIM + akq * 8;
    int c = col0 + j * 32 + arow;
    bSrc[j] = W1t + ((size_t)e * HDIM + c) * DDIM + akq * 8;
    wOff[j] = (j * 32 + arow) * PITCH + akq * 8;
  }

  int wave = t >> 6, lane = t & 63;
  int wr = wave >> 1, wc = wave & 1;
  int aBase = (wr * 64 + (lane & 15)) * PITCH + (lane >> 4) * 8;
  int bBase = (wc * 64 + (lane & 15)) * PITCH + (lane >> 4) * 8;

  f32x4 acc[4][4];
#pragma unroll
  for (int m = 0; m < 4; ++m)
#pragma unroll
    for (int nn = 0; nn < 4; ++nn) acc[m][nn] = (f32x4)0.0f;

  us8 aReg[4], bReg[4];
#pragma unroll
  for (int j = 0; j < 4; ++j) aReg[j] = *(const us8*)(aSrc[j]);
#pragma unroll
  for (int j = 0; j < 4; ++j) bReg[j] = *(const us8*)(bSrc[j]);
#pragma unroll
  for (int j = 0; j < 4; ++j) *(us8*)&sA[wOff[j]] = aReg[j];
#pragma unroll
  for (int j = 0; j < 4; ++j) *(us8*)&sB[wOff[j]] = bReg[j];
  __syncthreads();

  const int NKT = DDIM / BK;  // 16
  for (int kt = 0; kt < NKT; ++kt) {
    if (kt + 1 < NKT) {
#pragma unroll
      for (int j = 0; j < 4; ++j) aReg[j] = *(const us8*)(aSrc[j] + (kt + 1) * BK);
#pragma unroll
      for (int j = 0; j < 4; ++j) bReg[j] = *(const us8*)(bSrc[j] + (kt + 1) * BK);
    }
#pragma unroll
    for (int ks = 0; ks < 2; ++ks) {
      bf16x8 af[4], bfr[4];
#pragma unroll
      for (int m = 0; m < 4; ++m)
        af[m] = *(const bf16x8*)&sA[aBase + m * 16 * PITCH + ks * 32];
#pragma unroll
      for (int nn = 0; nn < 4; ++nn)
        bfr[nn] = *(const bf16x8*)&sB[bBase + nn * 16 * PITCH + ks * 32];
#pragma unroll
      for (int m = 0; m < 4; ++m)
#pragma unroll
        for (int nn = 0; nn < 4; ++nn)
          acc[m][nn] = __builtin_amdgcn_mfma_f32_16x16x32_bf16(
              af[m], bfr[nn], acc[m][nn], 0, 0, 0);
    }
    __syncthreads();
    if (kt + 1 < NKT) {
#pragma unroll
      for (int j = 0; j < 4; ++j) *(us8*)&sA[wOff[j]] = aReg[j];
#pragma unroll
      for (int j = 0; j < 4; ++j) *(us8*)&sB[wOff[j]] = bReg[j];
    }
    __syncthreads();
  }

  int cBase = col0 + wc * 64 + (lane & 15);
  float b1c[4];
#pragma unroll
  for (int nn = 0; nn < 4; ++nn) b1c[nn] = b1[e * HDIM + cBase + nn * 16];
#pragma unroll
  for (int m = 0; m < 4; ++m) {
#pragma unroll
    for (int q = 0; q < 4; ++q) {
      int rloc = wr * 64 + m * 16 + (lane >> 4) * 4 + q;
      if (row0 + rloc < ne) {
        int p = sTok[rloc];
        unsigned short* hr = h + (size_t)p * HDIM;
#pragma unroll
        for (int nn = 0; nn < 4; ++nn) {
          float v = acc[m][nn][q] + b1c[nn];
          v = fmaxf(v, 0.0f);
          hr[cBase + nn * 16] = f2bf(v);
        }
      }
    }
  }
}

// GEMM2: obuf[p, :] = h[p, :] @ W2t[e]^T + b2[e]   (bf16, NO atomics)
__global__ __launch_bounds__(256) void gemm2_kernel(
    const unsigned short* __restrict__ h, const unsigned short* __restrict__ W2t,
    const float* __restrict__ b2, const int* __restrict__ lists,
    const int* __restrict__ counts, const int* __restrict__ tiles,
    unsigned short* __restrict__ obuf) {
  int e, ne, row0, col0;
  if (!decode_tile(tiles, counts, e, ne, row0, col0)) return;

  __shared__ unsigned short sA[BM * PITCH];
  __shared__ unsigned short sB[BN * PITCH];
  __shared__ int sTok[BM];

  int t = threadIdx.x;
  if (t < BM) {
    int r = row0 + t;
    sTok[t] = (r < ne) ? lists[e * NTOK + r] : -1;
  }
  __syncthreads();

  int arow = t >> 3, akq = t & 7;
  const unsigned short* aSrc[4];
  const unsigned short* bSrc[4];
  int wOff[4];
#pragma unroll
  for (int j = 0; j < 4; ++j) {
    int p = sTok[j * 32 + arow];
    int pp = (p < 0) ? 0 : p;
    aSrc[j] = h + (size_t)pp * HDIM + akq * 8;
    int c = col0 + j * 32 + arow;
    bSrc[j] = W2t + ((size_t)e * CDIM + c) * HDIM + akq * 8;
    wOff[j] = (j * 32 + arow) * PITCH + akq * 8;
  }

  int wave = t >> 6, lane = t & 63;
  int wr = wave >> 1, wc = wave & 1;
  int aBase = (wr * 64 + (lane & 15)) * PITCH + (lane >> 4) * 8;
  int bBase = (wc * 64 + (lane & 15)) * PITCH + (lane >> 4) * 8;

  f32x4 acc[4][4];
#pragma unroll
  for (int m = 0; m < 4; ++m)
#pragma unroll
    for (int nn = 0; nn < 4; ++nn) acc[m][nn] = (f32x4)0.0f;

  us8 aReg[4], bReg[4];
#pragma unroll
  for (int j = 0; j < 4; ++j) aReg[j] = *(const us8*)(aSrc[j]);
#pragma unroll
  for (int j = 0; j < 4; ++j) bReg[j] = *(const us8*)(bSrc[j]);
#pragma unroll
  for (int j = 0; j < 4; ++j) *(us8*)&sA[wOff[j]] = aReg[j];
#pragma unroll
  for (int j = 0; j < 4; ++j) *(us8*)&sB[wOff[j]] = bReg[j];
  __syncthreads();

  const int NKT = HDIM / BK;  // 8
  for (int kt = 0; kt < NKT; ++kt) {
    if (kt + 1 < NKT) {
#pragma unroll
      for (int j = 0; j < 4; ++j) aReg[j] = *(const us8*)(aSrc[j] + (kt + 1) * BK);
#pragma unroll
      for (int j = 0; j < 4; ++j) bReg[j] = *(const us8*)(bSrc[j] + (kt + 1) * BK);
    }
#pragma unroll
    for (int ks = 0; ks < 2; ++ks) {
      bf16x8 af[4], bfr[4];
#pragma unroll
      for (int m = 0; m < 4; ++m)
        af[m] = *(const bf16x8*)&sA[aBase + m * 16 * PITCH + ks * 32];
#pragma unroll
      for (int nn = 0; nn < 4; ++nn)
        bfr[nn] = *(const bf16x8*)&sB[bBase + nn * 16 * PITCH + ks * 32];
#pragma unroll
      for (int m = 0; m < 4; ++m)
#pragma unroll
        for (int nn = 0; nn < 4; ++nn)
          acc[m][nn] = __builtin_amdgcn_mfma_f32_16x16x32_bf16(
              af[m], bfr[nn], acc[m][nn], 0, 0, 0);
    }
    __syncthreads();
    if (kt + 1 < NKT) {
#pragma unroll
      for (int j = 0; j < 4; ++j) *(us8*)&sA[wOff[j]] = aReg[j];
#pragma unroll
      for (int j = 0; j < 4; ++j) *(us8*)&sB[wOff[j]] = bReg[j];
    }
    __syncthreads();
  }

  int cBase = col0 + wc * 64 + (lane & 15);
  float b2c[4];
#pragma unroll
  for (int nn = 0; nn < 4; ++nn) b2c[nn] = b2[e * CDIM + cBase + nn * 16];
#pragma unroll
  for (int m = 0; m < 4; ++m) {
#pragma unroll
    for (int q = 0; q < 4; ++q) {
      int rloc = wr * 64 + m * 16 + (lane >> 4) * 4 + q;
      if (row0 + rloc < ne) {
        int p = sTok[rloc];
        unsigned short* orow = obuf + (size_t)p * CDIM;
#pragma unroll
        for (int nn = 0; nn < 4; ++nn)
          orow[cBase + nn * 16] = f2bf(acc[m][nn][q] + b2c[nn]);
      }
    }
  }
}

// ---------------------------------------------------------------------------
// Combine (in-place on d_out): out[n] = w0*obuf[2n] + w1*obuf[2n+1].
// Block b owns f32 rows [4b,4b+4) == byte range of pair rows [8b,8b+8):
// read-all -> barrier -> write-all; no cross-block overlap.
// ---------------------------------------------------------------------------
__global__ __launch_bounds__(256) void combine_kernel(
    const float* __restrict__ wpair, float* __restrict__ out) {
  const unsigned short* obuf = (const unsigned short*)out;
  int t = threadIdx.x;
  int n = blockIdx.x * 4 + (t >> 6);
  int c = (t & 63) * 8;
  us8 a = *(const us8*)&obuf[(size_t)(2 * n) * CDIM + c];
  us8 b = *(const us8*)&obuf[(size_t)(2 * n + 1) * CDIM + c];
  float w0 = wpair[2 * n], w1 = wpair[2 * n + 1];
  f32x4 r0, r1;
#pragma unroll
  for (int z = 0; z < 4; ++z) {
    r0[z] = w0 * bf2f(a[z]) + w1 * bf2f(b[z]);
    r1[z] = w0 * bf2f(a[z + 4]) + w1 * bf2f(b[z + 4]);
  }
  __syncthreads();
  *(f32x4*)&out[(size_t)n * CDIM + c] = r0;
  *(f32x4*)&out[(size_t)n * CDIM + c + 4] = r1;
}

// ---------------------------------------------------------------------------
extern "C" void kernel_launch(void* const* d_in, const int* in_sizes, int n_in,
                              void* d_out, int out_size, void* d_ws, size_t ws_size,
                              hipStream_t stream) {
  const float* x  = (const float*)d_in[0];
  const float* W1 = (const float*)d_in[1];
  const float* b1 = (const float*)d_in[2];
  const float* W2 = (const float*)d_in[3];
  const float* b2 = (const float*)d_in[4];
  const float* Wg = (const float*)d_in[5];
  const float* bg = (const float*)d_in[6];
  float* out = (float*)d_out;
  char* ws = (char*)d_ws;

  // workspace layout (~77.4 MiB)
  int* counts = (int*)ws;                                    // 256 B
  float* wpair = (float*)(ws + 256);                         // 256 KiB
  int* sel = (int*)(ws + 256 + 262144);                      // 128 KiB
  int* lists = (int*)(ws + 256 + 262144 + 131072);           // 1 MiB
  int* tiles = (int*)(ws + 256 + 262144 + 131072 + 1048576); // 8 KiB
  unsigned short* W1t = (unsigned short*)(ws + 256 + 262144 + 131072 + 1048576 + 8192);
  unsigned short* W2t = W1t + (size_t)NEXP * HDIM * DDIM;    // +8 MiB
  unsigned short* hbuf = W2t + (size_t)NEXP * CDIM * HDIM;   // +4 MiB, hbuf 64 MiB

  // d_out (64 MiB) triple-duty: xb (bf16 x) -> obuf (bf16 pair-rows) -> out.
  unsigned short* xb = (unsigned short*)d_out;
  unsigned short* obuf = (unsigned short*)d_out;

  hipLaunchKernelGGL(transpose_bf16_kernel, dim3(HDIM / 32, DDIM / 32, NEXP),
                     dim3(32, 8), 0, stream, W1, W1t, DDIM, HDIM);
  hipLaunchKernelGGL(transpose_bf16_kernel, dim3(CDIM / 32, HDIM / 32, NEXP),
                     dim3(32, 8), 0, stream, W2, W2t, HDIM, CDIM);
  hipLaunchKernelGGL(gate_kernel, dim3(NTOK / 32), dim3(256), 0, stream,
                     x, Wg, bg, sel, wpair, xb);
  hipLaunchKernelGGL(build_lists_kernel, dim3(NEXP), dim3(1024), 0, stream,
                     sel, counts, lists);
  hipLaunchKernelGGL(make_tiles_kernel, dim3(1), dim3(256), 0, stream,
                     counts, tiles);
  hipLaunchKernelGGL(gemm1_kernel, dim3((MAXTILE / 8) * 4 * 8), dim3(256),
                     0, stream, xb, W1t, b1, lists, counts, tiles, hbuf);
  hipLaunchKernelGGL(gemm2_kernel, dim3((MAXTILE / 8) * 4 * 8), dim3(256),
                     0, stream, hbuf, W2t, b2, lists, counts, tiles, obuf);
  hipLaunchKernelGGL(combine_kernel, dim3(NTOK / 4), dim3(256), 0, stream,
                     wpair, out);
}

// Round 8
// 248.466 us; speedup vs baseline: 4.5920x; 1.1954x over previous
//
#include <hip/hip_runtime.h>

// Problem constants
#define NTOK 32768
#define DDIM 1024
#define HDIM 512
#define CDIM 512
#define NEXP 8

#define BM 128
#define BN 128
#define BK 64
#define MAXTILE 520   // sum ceil(ne/128) <= 512 + 8

typedef __attribute__((ext_vector_type(8))) __bf16 bf16x8;
typedef __attribute__((ext_vector_type(4))) float f32x4;
typedef __attribute__((ext_vector_type(4))) unsigned short us4;
typedef __attribute__((ext_vector_type(8))) unsigned short us8;

static __device__ __forceinline__ unsigned short f2bf(float f) {
  union { float f; unsigned u; } v; v.f = f;
  unsigned u = v.u;
  u += 0x7FFFu + ((u >> 16) & 1u);   // RNE round to bf16
  return (unsigned short)(u >> 16);
}

static __device__ __forceinline__ float bf2f(unsigned short s) {
  union { unsigned u; float f; } v;
  v.u = ((unsigned)s) << 16;
  return v.f;
}

// HBM -> LDS direct DMA, 16B per lane. LDS dest = wave-uniform base + lane*16.
static __device__ __forceinline__ void gl_lds16(const void* g, void* l) {
  __builtin_amdgcn_global_load_lds(
      (const __attribute__((address_space(1))) unsigned int*)(unsigned long long)g,
      (__attribute__((address_space(3))) unsigned int*)(unsigned)(unsigned long long)l,
      16, 0, 0);
}

// Explicit LDS-DMA drain before barrier: the compiler's waitcnt insertion is
// not guaranteed to drain vmcnt for LDS-DMA at s_barrier (R7 post-timing race).
static __device__ __forceinline__ void fence_dma_then_barrier() {
  __builtin_amdgcn_sched_barrier(0);
  asm volatile("s_waitcnt vmcnt(0)" ::: "memory");
  __builtin_amdgcn_sched_barrier(0);
  __syncthreads();
}

static __device__ __forceinline__ void fence_lds_then_barrier() {
  __builtin_amdgcn_sched_barrier(0);
  asm volatile("s_waitcnt lgkmcnt(0)" ::: "memory");
  __builtin_amdgcn_sched_barrier(0);
  __syncthreads();
}

// ---------------------------------------------------------------------------
// Transpose [E][R][Cc] fp32 -> [E][Cc][R] bf16
// ---------------------------------------------------------------------------
__global__ __launch_bounds__(256) void transpose_bf16_kernel(
    const float* __restrict__ in, unsigned short* __restrict__ out,
    int R, int Cc) {
  __shared__ float tile[32][33];
  int e = blockIdx.z;
  int c0 = blockIdx.x * 32, r0 = blockIdx.y * 32;
  const float* src = in + (size_t)e * R * Cc;
  unsigned short* dst = out + (size_t)e * R * Cc;
  int tx = threadIdx.x, ty = threadIdx.y;  // (32, 8)
#pragma unroll
  for (int i = 0; i < 32; i += 8)
    tile[ty + i][tx] = src[(size_t)(r0 + ty + i) * Cc + (c0 + tx)];
  __syncthreads();
#pragma unroll
  for (int i = 0; i < 32; i += 8)
    dst[(size_t)(c0 + ty + i) * R + (r0 + tx)] = f2bf(tile[tx][ty + i]);
}

// ---------------------------------------------------------------------------
// Gate v4: scalar f32-Kahan logits + f64 combine, fused bf16-x emission.
// ---------------------------------------------------------------------------
#define GWPITCH 1064   // wg_lds expert pitch (words)
#define XSLOT 1056     // per-wave x slab words

__global__ __launch_bounds__(256) void gate_kernel(
    const float* __restrict__ x, const float* __restrict__ Wg,
    const float* __restrict__ bg, int* __restrict__ sel,
    float* __restrict__ wpair, unsigned short* __restrict__ xb) {
  __shared__ float wg_lds[NEXP * GWPITCH];   // ~34 KB, [e][d + 4*(d>>7)]
  __shared__ float xs[4][XSLOT];             // ~16.5 KB, per-wave slab

  int t = threadIdx.x;
  for (int i = t; i < DDIM * NEXP / 4; i += 256) {
    f32x4 v = *(const f32x4*)(Wg + (size_t)i * 4);
    int d = i >> 1;
    int e0 = (i & 1) * 4;
    int dsk = d + 4 * (d >> 7);
#pragma unroll
    for (int z = 0; z < 4; ++z)
      wg_lds[(e0 + z) * GWPITCH + dsk] = v[z];
  }
  __syncthreads();

  int wave = t >> 6, lane = t & 63;
  int g = lane >> 3, e = lane & 7;
  float* xslab = xs[wave];
  const float* wgrow = wg_lds + e * GWPITCH + g * 132;  // 128g + 4g skew
  const float* xsg = xslab + g * 132;
  double bge = (double)bg[e];

  int n0 = blockIdx.x * 32 + wave * 8;
  f32x4 ld[4], ldn[4];
  {
    const f32x4* xrow = (const f32x4*)(x + (size_t)n0 * DDIM);
#pragma unroll
    for (int j = 0; j < 4; ++j) ld[j] = xrow[j * 64 + lane];
  }

#pragma unroll 1
  for (int r = 0; r < 8; ++r) {
    int n = n0 + r;
    unsigned short* xbr = xb + (size_t)n * DDIM;
#pragma unroll
    for (int j = 0; j < 4; ++j) {
      int d0 = j * 256 + lane * 4;
      *(f32x4*)&xslab[d0 + 4 * (d0 >> 7)] = ld[j];
      us4 o;
#pragma unroll
      for (int z = 0; z < 4; ++z) o[z] = f2bf(ld[j][z]);
      *(us4*)&xbr[d0] = o;
    }
    if (r < 7) {
      const f32x4* xr2 = (const f32x4*)(x + (size_t)(n + 1) * DDIM);
#pragma unroll
      for (int j = 0; j < 4; ++j) ldn[j] = xr2[j * 64 + lane];
    }
    float s0 = 0.0f, c0 = 0.0f, s1 = 0.0f, c1 = 0.0f;
#pragma unroll
    for (int k = 0; k < 32; ++k) {
      f32x4 xv = *(const f32x4*)&xsg[4 * k];
      f32x4 wv = *(const f32x4*)&wgrow[4 * k];
#pragma unroll
      for (int z = 0; z < 4; z += 2) {
        float p0 = xv[z] * wv[z];
        float y0 = p0 - c0;
        float t0 = s0 + y0;
        c0 = (t0 - s0) - y0;
        s0 = t0;
        float p1 = xv[z + 1] * wv[z + 1];
        float y1 = p1 - c1;
        float t1 = s1 + y1;
        c1 = (t1 - s1) - y1;
        s1 = t1;
      }
    }
    double p = ((double)s0 + (double)c0) + ((double)s1 + (double)c1);
    p += __shfl_xor(p, 8, 64);
    p += __shfl_xor(p, 16, 64);
    p += __shfl_xor(p, 32, 64);
    double mylg = p + bge;
    double lg[NEXP];
#pragma unroll
    for (int ee = 0; ee < NEXP; ++ee) lg[ee] = __shfl(mylg, ee, 64);
    if (lane == 0) {
      int e0i = 0;
#pragma unroll
      for (int ee = 1; ee < NEXP; ++ee) if (lg[ee] > lg[e0i]) e0i = ee;  // earliest on tie
      int e1i = (e0i == 0) ? 1 : 0;
#pragma unroll
      for (int ee = 0; ee < NEXP; ++ee)
        if (ee != e0i && lg[ee] > lg[e1i]) e1i = ee;                     // earliest on tie
      float w1 = 1.0f / (1.0f + expf((float)(lg[e0i] - lg[e1i])));
      float w0 = 1.0f - w1;
      sel[n] = e0i | (e1i << 4);
      wpair[n * 2] = w0;
      wpair[n * 2 + 1] = w1;
    }
#pragma unroll
    for (int j = 0; j < 4; ++j) ld[j] = ldn[j];
  }
}

// ---------------------------------------------------------------------------
// Build per-expert pair lists via deterministic block-wide prefix scan.
// ---------------------------------------------------------------------------
__global__ __launch_bounds__(1024) void build_lists_kernel(
    const int* __restrict__ sel, int* __restrict__ counts,
    int* __restrict__ lists) {
  int e = blockIdx.x;
  int t = threadIdx.x;
  __shared__ int sc[1024];
  int base = t * (NTOK / 1024);
  int cnt = 0;
#pragma unroll
  for (int i = 0; i < NTOK / 1024; ++i) {
    int s = sel[base + i];
    cnt += ((s & 15) == e) || (((s >> 4) & 15) == e);
  }
  sc[t] = cnt;
  __syncthreads();
  for (int d = 1; d < 1024; d <<= 1) {
    int v = (t >= d) ? sc[t - d] : 0;
    __syncthreads();
    sc[t] += v;
    __syncthreads();
  }
  int off = sc[t] - cnt;
#pragma unroll
  for (int i = 0; i < NTOK / 1024; ++i) {
    int s = sel[base + i];
    if ((s & 15) == e)
      lists[e * NTOK + off++] = (base + i) * 2;
    else if (((s >> 4) & 15) == e)
      lists[e * NTOK + off++] = (base + i) * 2 + 1;
  }
  if (t == 1023) counts[e] = sc[1023];
}

// ---------------------------------------------------------------------------
// Tile table: tiles[0]=ntiles; tiles[1+2t]=expert, tiles[2+2t]=row0.
// ---------------------------------------------------------------------------
__global__ __launch_bounds__(256) void make_tiles_kernel(
    const int* __restrict__ counts, int* __restrict__ tiles) {
  __shared__ int off[NEXP + 1];
  int t = threadIdx.x;
  if (t == 0) {
    int s = 0;
    for (int e = 0; e < NEXP; ++e) { off[e] = s; s += (counts[e] + BM - 1) / BM; }
    off[NEXP] = s;
    tiles[0] = s;
  }
  __syncthreads();
  for (int e = 0; e < NEXP; ++e) {
    int base = off[e], cnt = off[e + 1] - off[e];
    for (int k = t; k < cnt; k += 256) {
      tiles[1 + 2 * (base + k)] = e;
      tiles[2 + 2 * (base + k)] = k * BM;
    }
  }
}

// ---------------------------------------------------------------------------
// XCD-chunked decode: grid = 65*4*8 = 2080 flat blocks.
// ---------------------------------------------------------------------------
static __device__ __forceinline__ bool decode_tile(
    const int* tiles, const int* counts, int& e, int& ne, int& row0, int& col0) {
  int i = blockIdx.x;
  int xcd = i & 7, slot = i >> 3;
  int col = slot & 3, tslot = slot >> 2;
  int rt = tslot * 8 + xcd;
  if (rt >= tiles[0]) return false;
  e = tiles[1 + 2 * rt];
  row0 = tiles[2 + 2 * rt];
  ne = counts[e];
  col0 = col * BN;
  return true;
}

// ---------------------------------------------------------------------------
// GEMM1: h[p,:] = relu( xb[tok(p),:] @ W1t[e]^T + b1[e] )  (bf16 out)
// global_load_lds staging, linear [128][64] LDS tiles, XOR slot^(row&7)
// swizzle on the per-lane SOURCE address + on the READ. Explicit DMA fences.
// ---------------------------------------------------------------------------
__global__ __launch_bounds__(256) void gemm1_kernel(
    const unsigned short* __restrict__ xb, const unsigned short* __restrict__ W1t,
    const float* __restrict__ b1, const int* __restrict__ lists,
    const int* __restrict__ counts, const int* __restrict__ tiles,
    unsigned short* __restrict__ h) {
  int e, ne, row0, col0;
  if (!decode_tile(tiles, counts, e, ne, row0, col0)) return;

  __shared__ __attribute__((aligned(128))) unsigned short sA[BM * BK];
  __shared__ __attribute__((aligned(128))) unsigned short sB[BN * BK];
  __shared__ int sTok[BM];

  int t = threadIdx.x;
  if (t < BM) {
    int r = row0 + t;
    sTok[t] = (r < ne) ? lists[e * NTOK + r] : -1;
  }
  __syncthreads();

  int srow = t >> 3;
  int sslot = (t & 7) ^ (srow & 7);
  const unsigned short* aSrc[4];
  const unsigned short* bSrc[4];
  unsigned short* aDst[4];
  unsigned short* bDst[4];
  int wbase = (t >> 6) * 512;   // wave-uniform LDS dest (shorts)
#pragma unroll
  for (int j = 0; j < 4; ++j) {
    int p = sTok[j * 32 + srow];
    int tok = (p < 0) ? 0 : (p >> 1);
    aSrc[j] = xb + (size_t)tok * DDIM + sslot * 8;
    int c = col0 + j * 32 + srow;
    bSrc[j] = W1t + ((size_t)e * HDIM + c) * DDIM + sslot * 8;
    aDst[j] = &sA[j * 2048 + wbase];
    bDst[j] = &sB[j * 2048 + wbase];
  }

  int wave = t >> 6, lane = t & 63;
  int wr = wave >> 1, wc = wave & 1;
  int fr = lane & 15, fg = lane >> 4;

  f32x4 acc[4][4];
#pragma unroll
  for (int m = 0; m < 4; ++m)
#pragma unroll
    for (int nn = 0; nn < 4; ++nn) acc[m][nn] = (f32x4)0.0f;

  const int NKT = DDIM / BK;  // 16
  for (int kt = 0; kt < NKT; ++kt) {
#pragma unroll
    for (int j = 0; j < 4; ++j) {
      gl_lds16(aSrc[j] + kt * BK, aDst[j]);
      gl_lds16(bSrc[j] + kt * BK, bDst[j]);
    }
    fence_dma_then_barrier();
#pragma unroll
    for (int ks = 0; ks < 2; ++ks) {
      int sl = (fg + ks * 4) ^ (fr & 7);   // swizzled read slot
      bf16x8 af[4], bfr[4];
#pragma unroll
      for (int m = 0; m < 4; ++m)
        af[m] = *(const bf16x8*)&sA[(wr * 64 + m * 16 + fr) * 64 + sl * 8];
#pragma unroll
      for (int nn = 0; nn < 4; ++nn)
        bfr[nn] = *(const bf16x8*)&sB[(wc * 64 + nn * 16 + fr) * 64 + sl * 8];
#pragma unroll
      for (int m = 0; m < 4; ++m)
#pragma unroll
        for (int nn = 0; nn < 4; ++nn)
          acc[m][nn] = __builtin_amdgcn_mfma_f32_16x16x32_bf16(
              af[m], bfr[nn], acc[m][nn], 0, 0, 0);
    }
    fence_lds_then_barrier();
  }

  int cBase = col0 + wc * 64 + fr;
  float b1c[4];
#pragma unroll
  for (int nn = 0; nn < 4; ++nn) b1c[nn] = b1[e * HDIM + cBase + nn * 16];
#pragma unroll
  for (int m = 0; m < 4; ++m) {
#pragma unroll
    for (int q = 0; q < 4; ++q) {
      int rloc = wr * 64 + m * 16 + fg * 4 + q;
      if (row0 + rloc < ne) {
        int p = sTok[rloc];
        unsigned short* hr = h + (size_t)p * HDIM;
#pragma unroll
        for (int nn = 0; nn < 4; ++nn) {
          float v = acc[m][nn][q] + b1c[nn];
          v = fmaxf(v, 0.0f);
          hr[cBase + nn * 16] = f2bf(v);
        }
      }
    }
  }
}

// ---------------------------------------------------------------------------
// GEMM2: obuf[p,:] = h[p,:] @ W2t[e]^T + b2[e]  (bf16, NO atomics)
// ---------------------------------------------------------------------------
__global__ __launch_bounds__(256) void gemm2_kernel(
    const unsigned short* __restrict__ h, const unsigned short* __restrict__ W2t,
    const float* __restrict__ b2, const int* __restrict__ lists,
    const int* __restrict__ counts, const int* __restrict__ tiles,
    unsigned short* __restrict__ obuf) {
  int e, ne, row0, col0;
  if (!decode_tile(tiles, counts, e, ne, row0, col0)) return;

  __shared__ __attribute__((aligned(128))) unsigned short sA[BM * BK];
  __shared__ __attribute__((aligned(128))) unsigned short sB[BN * BK];
  __shared__ int sTok[BM];

  int t = threadIdx.x;
  if (t < BM) {
    int r = row0 + t;
    sTok[t] = (r < ne) ? lists[e * NTOK + r] : -1;
  }
  __syncthreads();

  int srow = t >> 3;
  int sslot = (t & 7) ^ (srow & 7);
  const unsigned short* aSrc[4];
  const unsigned short* bSrc[4];
  unsigned short* aDst[4];
  unsigned short* bDst[4];
  int wbase = (t >> 6) * 512;
#pragma unroll
  for (int j = 0; j < 4; ++j) {
    int p = sTok[j * 32 + srow];
    int pp = (p < 0) ? 0 : p;
    aSrc[j] = h + (size_t)pp * HDIM + sslot * 8;
    int c = col0 + j * 32 + srow;
    bSrc[j] = W2t + ((size_t)e * CDIM + c) * HDIM + sslot * 8;
    aDst[j] = &sA[j * 2048 + wbase];
    bDst[j] = &sB[j * 2048 + wbase];
  }

  int wave = t >> 6, lane = t & 63;
  int wr = wave >> 1, wc = wave & 1;
  int fr = lane & 15, fg = lane >> 4;

  f32x4 acc[4][4];
#pragma unroll
  for (int m = 0; m < 4; ++m)
#pragma unroll
    for (int nn = 0; nn < 4; ++nn) acc[m][nn] = (f32x4)0.0f;

  const int NKT = HDIM / BK;  // 8
  for (int kt = 0; kt < NKT; ++kt) {
#pragma unroll
    for (int j = 0; j < 4; ++j) {
      gl_lds16(aSrc[j] + kt * BK, aDst[j]);
      gl_lds16(bSrc[j] + kt * BK, bDst[j]);
    }
    fence_dma_then_barrier();
#pragma unroll
    for (int ks = 0; ks < 2; ++ks) {
      int sl = (fg + ks * 4) ^ (fr & 7);
      bf16x8 af[4], bfr[4];
#pragma unroll
      for (int m = 0; m < 4; ++m)
        af[m] = *(const bf16x8*)&sA[(wr * 64 + m * 16 + fr) * 64 + sl * 8];
#pragma unroll
      for (int nn = 0; nn < 4; ++nn)
        bfr[nn] = *(const bf16x8*)&sB[(wc * 64 + nn * 16 + fr) * 64 + sl * 8];
#pragma unroll
      for (int m = 0; m < 4; ++m)
#pragma unroll
        for (int nn = 0; nn < 4; ++nn)
          acc[m][nn] = __builtin_amdgcn_mfma_f32_16x16x32_bf16(
              af[m], bfr[nn], acc[m][nn], 0, 0, 0);
    }
    fence_lds_then_barrier();
  }

  int cBase = col0 + wc * 64 + fr;
  float b2c[4];
#pragma unroll
  for (int nn = 0; nn < 4; ++nn) b2c[nn] = b2[e * CDIM + cBase + nn * 16];
#pragma unroll
  for (int m = 0; m < 4; ++m) {
#pragma unroll
    for (int q = 0; q < 4; ++q) {
      int rloc = wr * 64 + m * 16 + fg * 4 + q;
      if (row0 + rloc < ne) {
        int p = sTok[rloc];
        unsigned short* orow = obuf + (size_t)p * CDIM;
#pragma unroll
        for (int nn = 0; nn < 4; ++nn)
          orow[cBase + nn * 16] = f2bf(acc[m][nn][q] + b2c[nn]);
      }
    }
  }
}

// ---------------------------------------------------------------------------
// Combine (in-place on d_out): out[n] = w0*obuf[2n] + w1*obuf[2n+1].
// Each wave's reads and writes cover the same byte range (self-contained).
// ---------------------------------------------------------------------------
__global__ __launch_bounds__(256) void combine_kernel(
    const float* __restrict__ wpair, float* __restrict__ out) {
  const unsigned short* obuf = (const unsigned short*)out;
  int t = threadIdx.x;
  int n = blockIdx.x * 4 + (t >> 6);
  int c = (t & 63) * 8;
  us8 a = *(const us8*)&obuf[(size_t)(2 * n) * CDIM + c];
  us8 b = *(const us8*)&obuf[(size_t)(2 * n + 1) * CDIM + c];
  float w0 = wpair[2 * n], w1 = wpair[2 * n + 1];
  f32x4 r0, r1;
#pragma unroll
  for (int z = 0; z < 4; ++z) {
    r0[z] = w0 * bf2f(a[z]) + w1 * bf2f(b[z]);
    r1[z] = w0 * bf2f(a[z + 4]) + w1 * bf2f(b[z + 4]);
  }
  __syncthreads();
  *(f32x4*)&out[(size_t)n * CDIM + c] = r0;
  *(f32x4*)&out[(size_t)n * CDIM + c + 4] = r1;
}

// ---------------------------------------------------------------------------
extern "C" void kernel_launch(void* const* d_in, const int* in_sizes, int n_in,
                              void* d_out, int out_size, void* d_ws, size_t ws_size,
                              hipStream_t stream) {
  const float* x  = (const float*)d_in[0];
  const float* W1 = (const float*)d_in[1];
  const float* b1 = (const float*)d_in[2];
  const float* W2 = (const float*)d_in[3];
  const float* b2 = (const float*)d_in[4];
  const float* Wg = (const float*)d_in[5];
  const float* bg = (const float*)d_in[6];
  float* out = (float*)d_out;
  char* ws = (char*)d_ws;

  // workspace layout (~77.4 MiB)
  int* counts = (int*)ws;                                    // 256 B
  float* wpair = (float*)(ws + 256);                         // 256 KiB
  int* sel = (int*)(ws + 256 + 262144);                      // 128 KiB
  int* lists = (int*)(ws + 256 + 262144 + 131072);           // 1 MiB
  int* tiles = (int*)(ws + 256 + 262144 + 131072 + 1048576); // 8 KiB
  unsigned short* W1t = (unsigned short*)(ws + 256 + 262144 + 131072 + 1048576 + 8192);
  unsigned short* W2t = W1t + (size_t)NEXP * HDIM * DDIM;    // +8 MiB
  unsigned short* hbuf = W2t + (size_t)NEXP * CDIM * HDIM;   // +4 MiB, hbuf 64 MiB

  // d_out (64 MiB) triple-duty: xb (bf16 x) -> obuf (bf16 pair-rows) -> out.
  unsigned short* xb = (unsigned short*)d_out;
  unsigned short* obuf = (unsigned short*)d_out;

  hipLaunchKernelGGL(transpose_bf16_kernel, dim3(HDIM / 32, DDIM / 32, NEXP),
                     dim3(32, 8), 0, stream, W1, W1t, DDIM, HDIM);
  hipLaunchKernelGGL(transpose_bf16_kernel, dim3(CDIM / 32, HDIM / 32, NEXP),
                     dim3(32, 8), 0, stream, W2, W2t, HDIM, CDIM);
  hipLaunchKernelGGL(gate_kernel, dim3(NTOK / 32), dim3(256), 0, stream,
                     x, Wg, bg, sel, wpair, xb);
  hipLaunchKernelGGL(build_lists_kernel, dim3(NEXP), dim3(1024), 0, stream,
                     sel, counts, lists);
  hipLaunchKernelGGL(make_tiles_kernel, dim3(1), dim3(256), 0, stream,
                     counts, tiles);
  hipLaunchKernelGGL(gemm1_kernel, dim3((MAXTILE / 8) * 4 * 8), dim3(256),
                     0, stream, xb, W1t, b1, lists, counts, tiles, hbuf);
  hipLaunchKernelGGL(gemm2_kernel, dim3((MAXTILE / 8) * 4 * 8), dim3(256),
                     0, stream, hbuf, W2t, b2, lists, counts, tiles, obuf);
  hipLaunchKernelGGL(combine_kernel, dim3(NTOK / 4), dim3(256), 0, stream,
                     wpair, out);
}